// Round 1
// baseline (1756.476 us; speedup 1.0000x reference)
//
#include <hip/hip_runtime.h>

typedef unsigned short u16;
typedef unsigned int   u32;
typedef __attribute__((ext_vector_type(4))) float f32x4;
typedef __attribute__((ext_vector_type(8))) short s16x8;

#define TT 12
#define NN 10000
#define EE 160000
#define DD 128
#define OO 64

__device__ __forceinline__ u16 f2bf(float f) {
  union { float f; u32 u; } x; x.f = f;
  u32 r = x.u + 0x7FFFu + ((x.u >> 16) & 1u);   // RNE
  return (u16)(r >> 16);
}

// ---------------- CSR build ----------------
__global__ __launch_bounds__(256) void count_kernel(const int* __restrict__ dst,
                                                    int* __restrict__ deg, int E) {
  int e = blockIdx.x * 256 + threadIdx.x;
  if (e < E) atomicAdd(&deg[dst[e]], 1);
}

__global__ __launch_bounds__(1024) void scan_kernel(const int* __restrict__ deg,
                                                    int* __restrict__ offs,
                                                    float* __restrict__ dinv, int n) {
  __shared__ int buf[1024];
  __shared__ int carry_s;
  int tid = threadIdx.x;
  if (tid == 0) carry_s = 0;
  __syncthreads();
  for (int base = 0; base < n; base += 1024) {
    int v = (base + tid < n) ? deg[base + tid] : 0;
    buf[tid] = v;
    __syncthreads();
    for (int off = 1; off < 1024; off <<= 1) {
      int t = (tid >= off) ? buf[tid - off] : 0;
      __syncthreads();
      buf[tid] += t;
      __syncthreads();
    }
    int carry = carry_s;
    if (base + tid < n) {
      offs[base + tid] = carry + buf[tid] - v;          // exclusive
      dinv[base + tid] = (v > 0) ? 1.0f / (float)v : 0.0f;
    }
    __syncthreads();
    if (tid == 1023) carry_s = carry + buf[1023];
    __syncthreads();
  }
  if (tid == 0) offs[n] = carry_s;
}

__global__ __launch_bounds__(256) void fill_kernel(const int* __restrict__ src,
                                                   const int* __restrict__ dst,
                                                   const int* __restrict__ offs,
                                                   int* __restrict__ cursor,
                                                   int* __restrict__ csr, int E) {
  int e = blockIdx.x * 256 + threadIdx.x;
  if (e >= E) return;
  int d = dst[e];
  int pos = atomicAdd(&cursor[d], 1);
  csr[offs[d] + pos] = src[e];
}

// ---------------- weight/bias packing ----------------
// Wp layout per layer: [256 cols][512 k] bf16 (B^T), k-segs: 0:xin 1:agg(xin) 2:h 3:agg(h)
// cols 0-127 = u-gate (Ws2/Wn2/Ws3/Wn3), 128-255 = c-gate (Ws4/Wn4/Ws5/Wn5)
__global__ __launch_bounds__(256) void pack_kernel(const float* __restrict__ Wself,
                                                   const float* __restrict__ Wneigh,
                                                   const float* __restrict__ b,
                                                   const float* __restrict__ Wout,
                                                   u16* __restrict__ Wp,
                                                   float* __restrict__ biasbuf,
                                                   u16* __restrict__ WoT) {
  int gid = blockIdx.x * 256 + threadIdx.x;
  const int NWP = 2 * 256 * 512;
  if (gid < NWP) {
    int j = gid >> 17;
    int rem = gid & 131071;
    int c = rem >> 9;
    int k = rem & 511;
    int seg = k >> 7, kd = k & 127;
    int cc = c & 127;
    int gate = (c < 128) ? (seg < 2 ? 2 : 3) : (seg < 2 ? 4 : 5);
    const float* M = (seg & 1) ? Wneigh : Wself;
    float v = M[((j * 6 + gate) * 128 + kd) * 128 + cc];
    Wp[gid] = f2bf(v);
  } else if (gid < NWP + 64 * 128) {
    int i = gid - NWP;
    int c = i >> 7, k = i & 127;                 // WoT[c][k] = Wout[k][c]
    WoT[i] = f2bf(Wout[k * OO + c]);
  } else if (gid < NWP + 64 * 128 + 512) {
    int i = gid - NWP - 64 * 128;
    int j = i >> 8, g = (i >> 7) & 1, d = i & 127;
    int g1 = g ? 4 : 2, g2 = g ? 5 : 3;
    biasbuf[i] = b[(j * 6 + g1) * 128 + d] + b[(j * 6 + g2) * 128 + d];
  }
}

// ---------------- graph aggregation (mean over in-neighbors) ----------------
// one wave per node, 2 floats per lane = 128 features; up to 3 sources fused
template <int NS>
__global__ __launch_bounds__(256) void agg_kernel(const int* __restrict__ offs,
                                                  const int* __restrict__ csr,
                                                  const float* __restrict__ dinv,
                                                  const float* __restrict__ s0,
                                                  const float* __restrict__ s1,
                                                  const float* __restrict__ s2,
                                                  float* __restrict__ o0,
                                                  float* __restrict__ o1,
                                                  float* __restrict__ o2, int N) {
  int wid = (blockIdx.x * 256 + threadIdx.x) >> 6;
  int lane = threadIdx.x & 63;
  if (wid >= N) return;
  int e0 = offs[wid], e1 = offs[wid + 1];
  float di = dinv[wid];
  int fo = lane * 2;
  float a0x = 0.f, a0y = 0.f, a1x = 0.f, a1y = 0.f, a2x = 0.f, a2y = 0.f;
  for (int e = e0; e < e1; ++e) {
    int s = csr[e] * DD + fo;
    float2 v0 = *(const float2*)(s0 + s); a0x += v0.x; a0y += v0.y;
    if constexpr (NS > 1) { float2 v1 = *(const float2*)(s1 + s); a1x += v1.x; a1y += v1.y; }
    if constexpr (NS > 2) { float2 v2 = *(const float2*)(s2 + s); a2x += v2.x; a2y += v2.y; }
  }
  int o = wid * DD + fo;
  *(float2*)(o0 + o) = make_float2(a0x * di, a0y * di);
  if constexpr (NS > 1) *(float2*)(o1 + o) = make_float2(a1x * di, a1y * di);
  if constexpr (NS > 2) *(float2*)(o2 + o) = make_float2(a2x * di, a2y * di);
}

// ---------------- fused GRU-ish cell: C[N,256]=A[N,512]@W, sigmoid/tanh, h'=u*h+(1-u)*c ----------------
// block = 256 thr (4 waves), tile 32 rows x 256 cols; in-place h update (rows block-exclusive)
__global__ __launch_bounds__(256) void cell_kernel(const float* __restrict__ xin,
                                                   const float* __restrict__ ax,
                                                   float* __restrict__ h,
                                                   const float* __restrict__ ah,
                                                   const u16* __restrict__ Wp,   // this layer [256][512]
                                                   const float* __restrict__ bias, // [2][128]
                                                   int N) {
  __shared__ __align__(16) u16 As[32 * 64];
  __shared__ __align__(16) u16 Bs[256 * 64];
  const float* srcs[4] = {xin, ax, h, ah};
  int tid = threadIdx.x;
  int lane = tid & 63;
  int w = tid >> 6;
  int wr = w & 1, wc = w >> 1;
  int row0 = blockIdx.x * 32;

  f32x4 accU[4] = {};
  f32x4 accC[4] = {};

  for (int kc = 0; kc < 8; ++kc) {
    // ---- stage A (32x64, fp32 -> bf16, XOR-swizzled) ----
    {
      int r = tid >> 3;
      int k8 = (tid & 7) * 8;
      const float* sp = srcs[kc >> 1];
      int grow = row0 + r;
      float4 va, vb;
      if (grow < N) {
        const float* p = sp + (size_t)grow * DD + (kc & 1) * 64 + k8;
        va = *(const float4*)p;
        vb = *(const float4*)(p + 4);
      } else {
        va = make_float4(0, 0, 0, 0); vb = va;
      }
      uint4 pk;
      pk.x = (u32)f2bf(va.x) | ((u32)f2bf(va.y) << 16);
      pk.y = (u32)f2bf(va.z) | ((u32)f2bf(va.w) << 16);
      pk.z = (u32)f2bf(vb.x) | ((u32)f2bf(vb.y) << 16);
      pk.w = (u32)f2bf(vb.z) | ((u32)f2bf(vb.w) << 16);
      int byte = (r * 128 + (tid & 7) * 16) ^ ((r & 7) << 4);
      *(uint4*)((char*)As + byte) = pk;
    }
    // ---- stage B (256x64 bf16 from packed W^T, XOR-swizzled) ----
    {
      int k8 = (tid & 7) * 8;
      #pragma unroll
      for (int it = 0; it < 8; ++it) {
        int c = it * 32 + (tid >> 3);
        uint4 v = *(const uint4*)(Wp + c * 512 + kc * 64 + k8);
        int byte = (c * 128 + (tid & 7) * 16) ^ ((c & 7) << 4);
        *(uint4*)((char*)Bs + byte) = v;
      }
    }
    __syncthreads();
    // ---- compute: 2 k-subs of 32 ----
    #pragma unroll
    for (int ks = 0; ks < 2; ++ks) {
      int arow = wr * 16 + (lane & 15);
      int abyte = (arow * 128 + ks * 64 + (lane >> 4) * 16) ^ ((arow & 7) << 4);
      s16x8 af = *(const s16x8*)((char*)As + abyte);
      #pragma unroll
      for (int n = 0; n < 4; ++n) {
        int cu = wc * 64 + n * 16 + (lane & 15);
        int bbu = (cu * 128 + ks * 64 + (lane >> 4) * 16) ^ ((cu & 7) << 4);
        s16x8 bu = *(const s16x8*)((char*)Bs + bbu);
        accU[n] = __builtin_amdgcn_mfma_f32_16x16x32_bf16(af, bu, accU[n], 0, 0, 0);
        int cc = cu + 128;
        int bbc = (cc * 128 + ks * 64 + (lane >> 4) * 16) ^ ((cc & 7) << 4);
        s16x8 bc = *(const s16x8*)((char*)Bs + bbc);
        accC[n] = __builtin_amdgcn_mfma_f32_16x16x32_bf16(af, bc, accC[n], 0, 0, 0);
      }
    }
    __syncthreads();
  }

  // ---- epilogue: u=sigmoid, c=tanh, h' = u*h + (1-u)*c (fp32, in-place) ----
  #pragma unroll
  for (int n = 0; n < 4; ++n) {
    int col = wc * 64 + n * 16 + (lane & 15);
    float bu = bias[col], bc = bias[128 + col];
    #pragma unroll
    for (int r = 0; r < 4; ++r) {
      int row = row0 + wr * 16 + (lane >> 4) * 4 + r;
      if (row < N) {
        float u = 1.0f / (1.0f + __expf(-(accU[n][r] + bu)));
        float cg = tanhf(accC[n][r] + bc);
        float ho = h[(size_t)row * DD + col];
        h[(size_t)row * DD + col] = u * ho + (1.0f - u) * cg;
      }
    }
  }
}

// ---------------- output GEMM: out[N,64] = h1[N,128] @ Wout + b_out ----------------
__global__ __launch_bounds__(256) void out_kernel(const float* __restrict__ h1,
                                                  const u16* __restrict__ WoT,  // [64][128]
                                                  const float* __restrict__ bout,
                                                  float* __restrict__ out, int N) {
  __shared__ __align__(16) u16 As[64 * 128];
  __shared__ __align__(16) u16 Bs[64 * 128];
  int tid = threadIdx.x, lane = tid & 63, w = tid >> 6;
  int row0 = blockIdx.x * 64;
  {
    int r = tid >> 2;
    int kk = (tid & 3) * 32;
    int grow = row0 + r;
    #pragma unroll
    for (int i = 0; i < 4; ++i) {
      float4 va, vb;
      if (grow < N) {
        const float* p = h1 + (size_t)grow * DD + kk + i * 8;
        va = *(const float4*)p; vb = *(const float4*)(p + 4);
      } else { va = make_float4(0, 0, 0, 0); vb = va; }
      uint4 pk;
      pk.x = (u32)f2bf(va.x) | ((u32)f2bf(va.y) << 16);
      pk.y = (u32)f2bf(va.z) | ((u32)f2bf(va.w) << 16);
      pk.z = (u32)f2bf(vb.x) | ((u32)f2bf(vb.y) << 16);
      pk.w = (u32)f2bf(vb.z) | ((u32)f2bf(vb.w) << 16);
      int byte = (r * 256 + (kk + i * 8) * 2) ^ ((r & 7) << 4);
      *(uint4*)((char*)As + byte) = pk;
    }
  }
  {
    int c = tid >> 2;
    int kk = (tid & 3) * 32;
    #pragma unroll
    for (int i = 0; i < 4; ++i) {
      uint4 v = *(const uint4*)(WoT + c * 128 + kk + i * 8);
      int byte = (c * 256 + (kk + i * 8) * 2) ^ ((c & 7) << 4);
      *(uint4*)((char*)Bs + byte) = v;
    }
  }
  __syncthreads();
  f32x4 acc[4] = {};
  #pragma unroll
  for (int ks = 0; ks < 4; ++ks) {
    int arow = w * 16 + (lane & 15);
    int abyte = (arow * 256 + ks * 64 + (lane >> 4) * 16) ^ ((arow & 7) << 4);
    s16x8 af = *(const s16x8*)((char*)As + abyte);
    #pragma unroll
    for (int n = 0; n < 4; ++n) {
      int col = n * 16 + (lane & 15);
      int bbyte = (col * 256 + ks * 64 + (lane >> 4) * 16) ^ ((col & 7) << 4);
      s16x8 bf = *(const s16x8*)((char*)Bs + bbyte);
      acc[n] = __builtin_amdgcn_mfma_f32_16x16x32_bf16(af, bf, acc[n], 0, 0, 0);
    }
  }
  #pragma unroll
  for (int n = 0; n < 4; ++n) {
    int col = n * 16 + (lane & 15);
    float bb = bout[col];
    #pragma unroll
    for (int r = 0; r < 4; ++r) {
      int row = row0 + w * 16 + (lane >> 4) * 4 + r;
      if (row < N) out[(size_t)row * OO + col] = acc[n][r] + bb;
    }
  }
}

extern "C" void kernel_launch(void* const* d_in, const int* in_sizes, int n_in,
                              void* d_out, int out_size, void* d_ws, size_t ws_size,
                              hipStream_t stream) {
  const float* x      = (const float*)d_in[0];  // [T,N,D]
  const float* hs     = (const float*)d_in[1];  // [L,N,D]
  const float* Wself  = (const float*)d_in[2];  // [L,6,D,D]
  const float* Wneigh = (const float*)d_in[3];
  const float* b      = (const float*)d_in[4];  // [L,6,D]
  const float* Wout   = (const float*)d_in[5];  // [D,OUT]
  const float* bout   = (const float*)d_in[6];  // [OUT]
  const int*   src    = (const int*)d_in[7];    // [E]
  const int*   dst    = (const int*)d_in[8];    // [E]
  float* out = (float*)d_out;

  const int N = NN, E = EE, D = DD, T = TT;

  char* ws = (char*)d_ws;
  size_t off = 0;
  auto alloc = [&](size_t bytes) -> void* {
    void* p = ws + off;
    off = (off + bytes + 255) & ~(size_t)255;
    return p;
  };
  int*   deg     = (int*)alloc(N * 4);
  int*   offs    = (int*)alloc((N + 1) * 4);
  int*   cursor  = (int*)alloc(N * 4);
  int*   csr     = (int*)alloc(E * 4);
  float* dinv    = (float*)alloc(N * 4);
  u16*   Wp      = (u16*)alloc(2 * 256 * 512 * 2);
  float* biasbuf = (float*)alloc(512 * 4);
  u16*   WoT     = (u16*)alloc(64 * 128 * 2);
  float* h0      = (float*)alloc((size_t)N * D * 4);
  float* h1      = (float*)alloc((size_t)N * D * 4);
  float* ax      = (float*)alloc((size_t)N * D * 4);
  float* ah0     = (float*)alloc((size_t)N * D * 4);
  float* ah1     = (float*)alloc((size_t)N * D * 4);
  float* ah0n    = (float*)alloc((size_t)N * D * 4);

  hipMemsetAsync(deg, 0, N * 4, stream);
  hipMemsetAsync(cursor, 0, N * 4, stream);
  count_kernel<<<(E + 255) / 256, 256, 0, stream>>>(dst, deg, E);
  scan_kernel<<<1, 1024, 0, stream>>>(deg, offs, dinv, N);
  fill_kernel<<<(E + 255) / 256, 256, 0, stream>>>(src, dst, offs, cursor, csr, E);
  {
    int tot = 2 * 256 * 512 + 64 * 128 + 512;
    pack_kernel<<<(tot + 255) / 256, 256, 0, stream>>>(Wself, Wneigh, b, Wout, Wp, biasbuf, WoT);
  }
  hipMemcpyAsync(h0, hs, (size_t)N * D * 4, hipMemcpyDeviceToDevice, stream);
  hipMemcpyAsync(h1, hs + (size_t)N * D, (size_t)N * D * 4, hipMemcpyDeviceToDevice, stream);

  int aggGrid  = (N + 3) / 4;        // 4 waves/block, 1 node/wave
  int cellGrid = (N + 31) / 32;
  int outGrid  = (N + 63) / 64;

  for (int t = 0; t < T; ++t) {
    const float* xt = x + (size_t)t * N * D;
    // agg of x_t, h0_prev, h1_prev (fused, 3 sources over same CSR)
    agg_kernel<3><<<aggGrid, 256, 0, stream>>>(offs, csr, dinv, xt, h0, h1, ax, ah0, ah1, N);
    // layer 0: h0 <- cell(x_t, ax, h0, ah0)
    cell_kernel<<<cellGrid, 256, 0, stream>>>(xt, ax, h0, ah0, Wp, biasbuf, N);
    // agg of fresh h0 (layer-1 hN_x)
    agg_kernel<1><<<aggGrid, 256, 0, stream>>>(offs, csr, dinv, h0, h0, h0, ah0n, ah0n, ah0n, N);
    // layer 1: h1 <- cell(h0, ah0n, h1, ah1)
    cell_kernel<<<cellGrid, 256, 0, stream>>>(h0, ah0n, h1, ah1, Wp + 131072, biasbuf + 256, N);
    // out[t] = h1 @ Wout + bout
    out_kernel<<<outGrid, 256, 0, stream>>>(h1, WoT, bout, out + (size_t)t * N * OO, N);
  }
  // hidden_final
  hipMemcpyAsync(out + (size_t)T * N * OO, h0, (size_t)N * D * 4, hipMemcpyDeviceToDevice, stream);
  hipMemcpyAsync(out + (size_t)T * N * OO + (size_t)N * D, h1, (size_t)N * D * 4, hipMemcpyDeviceToDevice, stream);
}

// Round 2
// 1265.961 us; speedup vs baseline: 1.3875x; 1.3875x over previous
//
#include <hip/hip_runtime.h>

typedef unsigned short u16;
typedef unsigned int   u32;
typedef __attribute__((ext_vector_type(4))) float f32x4;
typedef __attribute__((ext_vector_type(8))) short s16x8;

#define TT 12
#define NN 10000
#define EE 160000
#define DD 128
#define OO 64

__device__ __forceinline__ u16 f2bf(float f) {
  union { float f; u32 u; } x; x.f = f;
  u32 r = x.u + 0x7FFFu + ((x.u >> 16) & 1u);   // RNE
  return (u16)(r >> 16);
}
__device__ __forceinline__ float bf2f(u16 v) {
  union { u32 u; float f; } x; x.u = (u32)v << 16; return x.f;
}

// ---------------- CSR build ----------------
__global__ __launch_bounds__(256) void count_kernel(const int* __restrict__ dst,
                                                    int* __restrict__ deg, int E) {
  int e = blockIdx.x * 256 + threadIdx.x;
  if (e < E) atomicAdd(&deg[dst[e]], 1);
}

__global__ __launch_bounds__(1024) void scan_kernel(const int* __restrict__ deg,
                                                    int* __restrict__ offs,
                                                    float* __restrict__ dinv, int n) {
  __shared__ int buf[1024];
  __shared__ int carry_s;
  int tid = threadIdx.x;
  if (tid == 0) carry_s = 0;
  __syncthreads();
  for (int base = 0; base < n; base += 1024) {
    int v = (base + tid < n) ? deg[base + tid] : 0;
    buf[tid] = v;
    __syncthreads();
    for (int off = 1; off < 1024; off <<= 1) {
      int t = (tid >= off) ? buf[tid - off] : 0;
      __syncthreads();
      buf[tid] += t;
      __syncthreads();
    }
    int carry = carry_s;
    if (base + tid < n) {
      offs[base + tid] = carry + buf[tid] - v;          // exclusive
      dinv[base + tid] = (v > 0) ? 1.0f / (float)v : 0.0f;
    }
    __syncthreads();
    if (tid == 1023) carry_s = carry + buf[1023];
    __syncthreads();
  }
  if (tid == 0) offs[n] = carry_s;
}

__global__ __launch_bounds__(256) void fill_kernel(const int* __restrict__ src,
                                                   const int* __restrict__ dst,
                                                   const int* __restrict__ offs,
                                                   int* __restrict__ cursor,
                                                   int* __restrict__ csr, int E) {
  int e = blockIdx.x * 256 + threadIdx.x;
  if (e >= E) return;
  int d = dst[e];
  int pos = atomicAdd(&cursor[d], 1);
  csr[offs[d] + pos] = src[e];
}

// ---------------- weight/bias packing ----------------
// Wp layout per layer: [256 cols][512 k] bf16 (B^T), k-segs: 0:xin 1:agg(xin) 2:h 3:agg(h)
// cols 0-127 = u-gate (gates 2/3), 128-255 = c-gate (gates 4/5)
__global__ __launch_bounds__(256) void pack_kernel(const float* __restrict__ Wself,
                                                   const float* __restrict__ Wneigh,
                                                   const float* __restrict__ b,
                                                   const float* __restrict__ Wout,
                                                   u16* __restrict__ Wp,
                                                   float* __restrict__ biasbuf,
                                                   u16* __restrict__ WoT) {
  int gid = blockIdx.x * 256 + threadIdx.x;
  const int NWP = 2 * 256 * 512;
  if (gid < NWP) {
    int j = gid >> 17;
    int rem = gid & 131071;
    int c = rem >> 9;
    int k = rem & 511;
    int seg = k >> 7, kd = k & 127;
    int cc = c & 127;
    int gate = (c < 128) ? (seg < 2 ? 2 : 3) : (seg < 2 ? 4 : 5);
    const float* M = (seg & 1) ? Wneigh : Wself;
    float v = M[((j * 6 + gate) * 128 + kd) * 128 + cc];
    Wp[gid] = f2bf(v);
  } else if (gid < NWP + 64 * 128) {
    int i = gid - NWP;
    int c = i >> 7, k = i & 127;                 // WoT[c][k] = Wout[k][c]
    WoT[i] = f2bf(Wout[k * OO + c]);
  } else if (gid < NWP + 64 * 128 + 512) {
    int i = gid - NWP - 64 * 128;
    int j = i >> 8, g = (i >> 7) & 1, d = i & 127;
    int g1 = g ? 4 : 2, g2 = g ? 5 : 3;
    biasbuf[i] = b[(j * 6 + g1) * 128 + d] + b[(j * 6 + g2) * 128 + d];
  }
}

// ---------------- convert: x -> xb (bf16), hs -> hstate (f32) + hb (bf16) ----------------
__global__ __launch_bounds__(256) void cvt_kernel(const float* __restrict__ x,
                                                  const float* __restrict__ hs,
                                                  u16* __restrict__ xb,
                                                  float* __restrict__ hstate,
                                                  u16* __restrict__ hb,
                                                  int nx4, int nh4) {
  int i = blockIdx.x * 256 + threadIdx.x;
  if (i < nx4) {
    float4 v = *(const float4*)(x + (size_t)i * 4);
    uint2 p;
    p.x = (u32)f2bf(v.x) | ((u32)f2bf(v.y) << 16);
    p.y = (u32)f2bf(v.z) | ((u32)f2bf(v.w) << 16);
    *(uint2*)(xb + (size_t)i * 4) = p;
  } else if (i < nx4 + nh4) {
    int j = i - nx4;
    float4 v = *(const float4*)(hs + (size_t)j * 4);
    *(float4*)(hstate + (size_t)j * 4) = v;
    uint2 p;
    p.x = (u32)f2bf(v.x) | ((u32)f2bf(v.y) << 16);
    p.y = (u32)f2bf(v.z) | ((u32)f2bf(v.w) << 16);
    *(uint2*)(hb + (size_t)j * 4) = p;
  }
}

// ---------------- bf16 graph aggregation (mean over in-neighbors) ----------------
// one wave per node, 2 bf16 per lane; blockIdx.y offsets a [y][N][128] batch
template <int NS>
__global__ __launch_bounds__(256) void aggb_kernel(const int* __restrict__ offs,
                                                   const int* __restrict__ csr,
                                                   const float* __restrict__ dinv,
                                                   const u16* __restrict__ s0,
                                                   const u16* __restrict__ s1,
                                                   u16* __restrict__ o0,
                                                   u16* __restrict__ o1, int N) {
  int wid = (blockIdx.x * 256 + threadIdx.x) >> 6;
  if (wid >= N) return;
  int lane = threadIdx.x & 63;
  size_t toff = (size_t)blockIdx.y * N * DD;
  int e0 = offs[wid], e1 = offs[wid + 1];
  float di = dinv[wid];
  const u16* S0 = s0 + toff;
  const u16* S1 = s1 + toff;
  float a0 = 0.f, b0 = 0.f, a1 = 0.f, b1 = 0.f;
  for (int e = e0; e < e1; ++e) {
    int sidx = csr[e] * DD + lane * 2;
    u32 v0 = *(const u32*)(S0 + sidx);
    a0 += bf2f((u16)v0); b0 += bf2f((u16)(v0 >> 16));
    if constexpr (NS > 1) {
      u32 v1 = *(const u32*)(S1 + sidx);
      a1 += bf2f((u16)v1); b1 += bf2f((u16)(v1 >> 16));
    }
  }
  int oidx = wid * DD + lane * 2;
  *(u32*)(o0 + toff + oidx) = (u32)f2bf(a0 * di) | ((u32)f2bf(b0 * di) << 16);
  if constexpr (NS > 1)
    *(u32*)(o1 + toff + oidx) = (u32)f2bf(a1 * di) | ((u32)f2bf(b1 * di) << 16);
}

// ---------------- unified GEMM kernel ----------------
// tile 64 rows x 256 cols, 512 threads (8 waves: wr=w&3 row band, wc=w>>2 u/c col half)
// MODE 0: pre  — batched over blockIdx.y=t, A=[xb_t|axb_t] (NKC=4, k 0:256), store P
// MODE 1: cell0 — A=[h0b|ah0b] (NKC=4, W pre-offset to k 256:512), acc init from P,
//                 epilogue u/c -> h update (fp32 + bf16 shadow)
// MODE 2: cell1 — A=[h0b|ah0nb|h1b|ah1b] (NKC=8), h update + fused out GEMM
template <int MODE, int NKC>
__global__ __launch_bounds__(512) void mm_kernel(const u16* __restrict__ s0,
                                                 const u16* __restrict__ s1,
                                                 const u16* __restrict__ s2,
                                                 const u16* __restrict__ s3,
                                                 const u16* __restrict__ W,
                                                 const float* __restrict__ bias,
                                                 float* __restrict__ P,
                                                 float* __restrict__ h,
                                                 u16* __restrict__ hb,
                                                 const u16* __restrict__ WoT,
                                                 const float* __restrict__ bout,
                                                 float* __restrict__ outp, int N) {
  __shared__ __align__(16) char smem[40960];
  u16* As = (u16*)smem;              // 64x64 bf16, swizzled (8KB)
  u16* Bs = (u16*)(smem + 8192);     // 256x64 bf16, swizzled (32KB)
  const u16* srcs[4] = {s0, s1, s2, s3};
  int tid = threadIdx.x, lane = tid & 63, w = tid >> 6;
  int wr = w & 3, wc = w >> 2;
  int row0 = blockIdx.x * 64;
  size_t soff = 0;
  if constexpr (MODE == 0) {
    soff = (size_t)blockIdx.y * N * DD;
    P += (size_t)blockIdx.y * N * 256;
  }

  f32x4 accU[4], accC[4];
  if constexpr (MODE == 1) {
    #pragma unroll
    for (int n = 0; n < 4; ++n) {
      int col = wc * 64 + n * 16 + (lane & 15);
      #pragma unroll
      for (int r = 0; r < 4; ++r) {
        int row = row0 + wr * 16 + (lane >> 4) * 4 + r;
        accU[n][r] = (row < N) ? P[(size_t)row * 256 + col] : 0.f;
        accC[n][r] = (row < N) ? P[(size_t)row * 256 + col + 128] : 0.f;
      }
    }
  } else {
    #pragma unroll
    for (int n = 0; n < 4; ++n) { accU[n] = (f32x4){0,0,0,0}; accC[n] = (f32x4){0,0,0,0}; }
  }

  #pragma unroll
  for (int kc = 0; kc < NKC; ++kc) {
    // ---- stage A (64x64 bf16, XOR-swizzled) ----
    {
      int r = tid >> 3, k8 = (tid & 7) * 8;
      const u16* sp = srcs[kc >> 1] + soff;
      int grow = row0 + r;
      uint4 v = make_uint4(0, 0, 0, 0);
      if (grow < N) v = *(const uint4*)(sp + (size_t)grow * DD + (kc & 1) * 64 + k8);
      int byte = (r * 128 + (tid & 7) * 16) ^ ((r & 7) << 4);
      *(uint4*)((char*)As + byte) = v;
    }
    // ---- stage B (256x64 bf16, XOR-swizzled) ----
    #pragma unroll
    for (int it = 0; it < 4; ++it) {
      int id = it * 512 + tid;
      int c = id >> 3, k8 = (id & 7) * 8;
      uint4 v = *(const uint4*)(W + c * 512 + kc * 64 + k8);
      int byte = (c * 128 + (id & 7) * 16) ^ ((c & 7) << 4);
      *(uint4*)((char*)Bs + byte) = v;
    }
    __syncthreads();
    #pragma unroll
    for (int ks = 0; ks < 2; ++ks) {
      int arow = wr * 16 + (lane & 15);
      int abyte = (arow * 128 + ks * 64 + (lane >> 4) * 16) ^ ((arow & 7) << 4);
      s16x8 af = *(const s16x8*)((char*)As + abyte);
      #pragma unroll
      for (int n = 0; n < 4; ++n) {
        int cu = wc * 64 + n * 16 + (lane & 15);
        int bub = (cu * 128 + ks * 64 + (lane >> 4) * 16) ^ ((cu & 7) << 4);
        s16x8 bu = *(const s16x8*)((char*)Bs + bub);
        accU[n] = __builtin_amdgcn_mfma_f32_16x16x32_bf16(af, bu, accU[n], 0, 0, 0);
        int cc = cu + 128;
        int bcb = (cc * 128 + ks * 64 + (lane >> 4) * 16) ^ ((cc & 7) << 4);
        s16x8 bc = *(const s16x8*)((char*)Bs + bcb);
        accC[n] = __builtin_amdgcn_mfma_f32_16x16x32_bf16(af, bc, accC[n], 0, 0, 0);
      }
    }
    __syncthreads();
  }

  if constexpr (MODE == 0) {
    // store P (no bias/activation)
    #pragma unroll
    for (int n = 0; n < 4; ++n) {
      int col = wc * 64 + n * 16 + (lane & 15);
      #pragma unroll
      for (int r = 0; r < 4; ++r) {
        int row = row0 + wr * 16 + (lane >> 4) * 4 + r;
        if (row < N) {
          P[(size_t)row * 256 + col] = accU[n][r];
          P[(size_t)row * 256 + col + 128] = accC[n][r];
        }
      }
    }
  } else {
    // ---- epilogue: u=sigmoid, c=tanh, h' = u*h + (1-u)*c ----
    #pragma unroll
    for (int n = 0; n < 4; ++n) {
      int col = wc * 64 + n * 16 + (lane & 15);
      float bu = bias[col], bc = bias[128 + col];
      #pragma unroll
      for (int r = 0; r < 4; ++r) {
        int row = row0 + wr * 16 + (lane >> 4) * 4 + r;
        if (row < N) {
          float u = 1.0f / (1.0f + __expf(-(accU[n][r] + bu)));
          float cg = tanhf(accC[n][r] + bc);
          size_t idx = (size_t)row * DD + col;
          float hn = u * h[idx] + (1.0f - u) * cg;
          h[idx] = hn;
          u16 hnb = f2bf(hn);
          hb[idx] = hnb;
          if constexpr (MODE == 2) {
            int rl = row - row0;
            int hbyte = (rl * 256 + col * 2) ^ ((rl & 7) << 4);
            *(u16*)(smem + hbyte) = hnb;       // Hs overlays As/Bs (dead now)
          }
        }
      }
    }
    if constexpr (MODE == 2) {
      // stage WoT [64 cols][128 k] swizzled at smem+16384
      #pragma unroll
      for (int it = 0; it < 2; ++it) {
        int id = it * 512 + tid;
        int c = id >> 4, kc8 = (id & 15) * 8;
        uint4 v = *(const uint4*)(WoT + c * 128 + kc8);
        int byte = (c * 256 + kc8 * 2) ^ ((c & 7) << 4);
        *(uint4*)(smem + 16384 + byte) = v;
      }
      __syncthreads();
      // out tile 64x64: wave = (wr rows band, wc2 = w>>2 col half of 32)
      f32x4 ao[2] = {};
      #pragma unroll
      for (int ks = 0; ks < 4; ++ks) {
        int arow = wr * 16 + (lane & 15);
        int abyte = (arow * 256 + ks * 64 + (lane >> 4) * 16) ^ ((arow & 7) << 4);
        s16x8 af = *(const s16x8*)(smem + abyte);
        #pragma unroll
        for (int n = 0; n < 2; ++n) {
          int co = wc * 32 + n * 16 + (lane & 15);
          int bbyte = (co * 256 + ks * 64 + (lane >> 4) * 16) ^ ((co & 7) << 4);
          s16x8 bf = *(const s16x8*)(smem + 16384 + bbyte);
          ao[n] = __builtin_amdgcn_mfma_f32_16x16x32_bf16(af, bf, ao[n], 0, 0, 0);
        }
      }
      #pragma unroll
      for (int n = 0; n < 2; ++n) {
        int co = wc * 32 + n * 16 + (lane & 15);
        float bb = bout[co];
        #pragma unroll
        for (int r = 0; r < 4; ++r) {
          int row = row0 + wr * 16 + (lane >> 4) * 4 + r;
          if (row < N) outp[(size_t)row * OO + co] = ao[n][r] + bb;
        }
      }
    }
  }
}

extern "C" void kernel_launch(void* const* d_in, const int* in_sizes, int n_in,
                              void* d_out, int out_size, void* d_ws, size_t ws_size,
                              hipStream_t stream) {
  const float* x      = (const float*)d_in[0];  // [T,N,D]
  const float* hs     = (const float*)d_in[1];  // [L,N,D]
  const float* Wself  = (const float*)d_in[2];  // [L,6,D,D]
  const float* Wneigh = (const float*)d_in[3];
  const float* b      = (const float*)d_in[4];  // [L,6,D]
  const float* Wout   = (const float*)d_in[5];  // [D,OUT]
  const float* bout   = (const float*)d_in[6];  // [OUT]
  const int*   src    = (const int*)d_in[7];    // [E]
  const int*   dst    = (const int*)d_in[8];    // [E]
  float* out = (float*)d_out;

  const int N = NN, E = EE, D = DD, T = TT;

  char* ws = (char*)d_ws;
  size_t off = 0;
  auto alloc = [&](size_t bytes) -> void* {
    void* p = ws + off;
    off = (off + bytes + 255) & ~(size_t)255;
    return p;
  };
  int*   deg     = (int*)alloc(N * 4);
  int*   offs    = (int*)alloc((N + 1) * 4);
  int*   cursor  = (int*)alloc(N * 4);
  int*   csr     = (int*)alloc(E * 4);
  float* dinv    = (float*)alloc(N * 4);
  u16*   Wp      = (u16*)alloc(2 * 256 * 512 * 2);
  float* biasbuf = (float*)alloc(512 * 4);
  u16*   WoT     = (u16*)alloc(64 * 128 * 2);
  float* hstate  = (float*)alloc((size_t)2 * N * D * 4);   // [2][N][D] fp32 state
  u16*   hb      = (u16*)alloc((size_t)2 * N * D * 2);     // bf16 shadow
  u16*   ah0b    = (u16*)alloc((size_t)N * D * 2);
  u16*   ah1b    = (u16*)alloc((size_t)N * D * 2);
  u16*   xb      = (u16*)alloc((size_t)T * N * D * 2);
  u16*   axb     = (u16*)alloc((size_t)T * N * D * 2);
  float* P       = (float*)alloc((size_t)T * N * 256 * 4);

  float* h0  = hstate;
  float* h1  = hstate + (size_t)N * D;
  u16*   h0b = hb;
  u16*   h1b = hb + (size_t)N * D;

  hipMemsetAsync(deg, 0, N * 4, stream);
  hipMemsetAsync(cursor, 0, N * 4, stream);
  count_kernel<<<(E + 255) / 256, 256, 0, stream>>>(dst, deg, E);
  scan_kernel<<<1, 1024, 0, stream>>>(deg, offs, dinv, N);
  fill_kernel<<<(E + 255) / 256, 256, 0, stream>>>(src, dst, offs, cursor, csr, E);
  {
    int tot = 2 * 256 * 512 + 64 * 128 + 512;
    pack_kernel<<<(tot + 255) / 256, 256, 0, stream>>>(Wself, Wneigh, b, Wout, Wp, biasbuf, WoT);
  }
  {
    int nx4 = T * N * D / 4, nh4 = 2 * N * D / 4;
    cvt_kernel<<<(nx4 + nh4 + 255) / 256, 256, 0, stream>>>(x, hs, xb, hstate, hb, nx4, nh4);
  }

  int aggGrid  = (N * 64 + 255) / 256;   // 2500 blocks, 1 node/wave
  int mmGrid   = (N + 63) / 64;          // 157

  // agg(x_t) for all t, batched over grid.y
  aggb_kernel<1><<<dim3(aggGrid, T), 256, 0, stream>>>(offs, csr, dinv, xb, xb, axb, axb, N);
  // P[t] = [xb_t | axb_t] @ W_layer0[k 0:256], batched over grid.y
  mm_kernel<0, 4><<<dim3(mmGrid, T), 512, 0, stream>>>(xb, axb, xb, xb, Wp, biasbuf, P,
                                                       nullptr, nullptr, nullptr, nullptr,
                                                       nullptr, N);
  // initial agg of hidden states
  aggb_kernel<2><<<aggGrid, 256, 0, stream>>>(offs, csr, dinv, h0b, h1b, ah0b, ah1b, N);

  for (int t = 0; t < T; ++t) {
    // layer 0: h0 <- cell(x_t-part precomputed in P, h0, ah0)
    mm_kernel<1, 4><<<mmGrid, 512, 0, stream>>>(h0b, ah0b, h0b, h0b,
                                                Wp + 256, biasbuf,
                                                P + (size_t)t * N * 256,
                                                h0, h0b, nullptr, nullptr, nullptr, N);
    // agg(h0') — feeds cell1 (hN_x) AND next step's cell0 (hN_h): same value
    aggb_kernel<1><<<aggGrid, 256, 0, stream>>>(offs, csr, dinv, h0b, h0b, ah0b, ah0b, N);
    // layer 1 + fused out GEMM
    mm_kernel<2, 8><<<mmGrid, 512, 0, stream>>>(h0b, ah0b, h1b, ah1b,
                                                Wp + 131072, biasbuf + 256, nullptr,
                                                h1, h1b, WoT, bout,
                                                out + (size_t)t * N * OO, N);
    // agg(h1') for next step's cell1 hN_h
    if (t < T - 1)
      aggb_kernel<1><<<aggGrid, 256, 0, stream>>>(offs, csr, dinv, h1b, h1b, ah1b, ah1b, N);
  }
  // hidden_final = hstate [2][N][D]
  hipMemcpyAsync(out + (size_t)T * N * OO, hstate, (size_t)2 * N * D * 4,
                 hipMemcpyDeviceToDevice, stream);
}

// Round 3
// 899.257 us; speedup vs baseline: 1.9533x; 1.4078x over previous
//
#include <hip/hip_runtime.h>

typedef unsigned short u16;
typedef unsigned int   u32;
typedef __attribute__((ext_vector_type(4))) float f32x4;
typedef __attribute__((ext_vector_type(8))) short s16x8;

#define TT 12
#define NN 10000
#define EE 160000
#define DD 128
#define OO 64

__device__ __forceinline__ u16 f2bf(float f) {
  union { float f; u32 u; } x; x.f = f;
  u32 r = x.u + 0x7FFFu + ((x.u >> 16) & 1u);   // RNE
  return (u16)(r >> 16);
}
__device__ __forceinline__ float bf2f(u16 v) {
  union { u32 u; float f; } x; x.u = (u32)v << 16; return x.f;
}

// ---------------- CSR build ----------------
__global__ __launch_bounds__(256) void count_kernel(const int* __restrict__ dst,
                                                    int* __restrict__ deg, int E) {
  int e = blockIdx.x * 256 + threadIdx.x;
  if (e < E) atomicAdd(&deg[dst[e]], 1);
}

__global__ __launch_bounds__(1024) void scan_kernel(const int* __restrict__ deg,
                                                    int* __restrict__ offs,
                                                    float* __restrict__ dinv, int n) {
  __shared__ int buf[1024];
  __shared__ int carry_s;
  int tid = threadIdx.x;
  if (tid == 0) carry_s = 0;
  __syncthreads();
  for (int base = 0; base < n; base += 1024) {
    int v = (base + tid < n) ? deg[base + tid] : 0;
    buf[tid] = v;
    __syncthreads();
    for (int off = 1; off < 1024; off <<= 1) {
      int t = (tid >= off) ? buf[tid - off] : 0;
      __syncthreads();
      buf[tid] += t;
      __syncthreads();
    }
    int carry = carry_s;
    if (base + tid < n) {
      offs[base + tid] = carry + buf[tid] - v;          // exclusive
      dinv[base + tid] = (v > 0) ? 1.0f / (float)v : 0.0f;
    }
    __syncthreads();
    if (tid == 1023) carry_s = carry + buf[1023];
    __syncthreads();
  }
  if (tid == 0) offs[n] = carry_s;
}

__global__ __launch_bounds__(256) void fill_kernel(const int* __restrict__ src,
                                                   const int* __restrict__ dst,
                                                   const int* __restrict__ offs,
                                                   int* __restrict__ cursor,
                                                   int* __restrict__ csr, int E) {
  int e = blockIdx.x * 256 + threadIdx.x;
  if (e >= E) return;
  int d = dst[e];
  int pos = atomicAdd(&cursor[d], 1);
  csr[offs[d] + pos] = src[e];
}

// ---------------- weight/bias packing ----------------
__global__ __launch_bounds__(256) void pack_kernel(const float* __restrict__ Wself,
                                                   const float* __restrict__ Wneigh,
                                                   const float* __restrict__ b,
                                                   const float* __restrict__ Wout,
                                                   u16* __restrict__ Wp,
                                                   float* __restrict__ biasbuf,
                                                   u16* __restrict__ WoT) {
  int gid = blockIdx.x * 256 + threadIdx.x;
  const int NWP = 2 * 256 * 512;
  if (gid < NWP) {
    int j = gid >> 17;
    int rem = gid & 131071;
    int c = rem >> 9;
    int k = rem & 511;
    int seg = k >> 7, kd = k & 127;
    int cc = c & 127;
    int gate = (c < 128) ? (seg < 2 ? 2 : 3) : (seg < 2 ? 4 : 5);
    const float* M = (seg & 1) ? Wneigh : Wself;
    float v = M[((j * 6 + gate) * 128 + kd) * 128 + cc];
    Wp[gid] = f2bf(v);
  } else if (gid < NWP + 64 * 128) {
    int i = gid - NWP;
    int c = i >> 7, k = i & 127;                 // WoT[c][k] = Wout[k][c]
    WoT[i] = f2bf(Wout[k * OO + c]);
  } else if (gid < NWP + 64 * 128 + 512) {
    int i = gid - NWP - 64 * 128;
    int j = i >> 8, g = (i >> 7) & 1, d = i & 127;
    int g1 = g ? 4 : 2, g2 = g ? 5 : 3;
    biasbuf[i] = b[(j * 6 + g1) * 128 + d] + b[(j * 6 + g2) * 128 + d];
  }
}

// ---------------- convert: x -> xb (bf16), hs -> hstate (f32) + hb (bf16) ----------------
__global__ __launch_bounds__(256) void cvt_kernel(const float* __restrict__ x,
                                                  const float* __restrict__ hs,
                                                  u16* __restrict__ xb,
                                                  float* __restrict__ hstate,
                                                  u16* __restrict__ hb,
                                                  int nx4, int nh4) {
  int i = blockIdx.x * 256 + threadIdx.x;
  if (i < nx4) {
    float4 v = *(const float4*)(x + (size_t)i * 4);
    uint2 p;
    p.x = (u32)f2bf(v.x) | ((u32)f2bf(v.y) << 16);
    p.y = (u32)f2bf(v.z) | ((u32)f2bf(v.w) << 16);
    *(uint2*)(xb + (size_t)i * 4) = p;
  } else if (i < nx4 + nh4) {
    int j = i - nx4;
    float4 v = *(const float4*)(hs + (size_t)j * 4);
    *(float4*)(hstate + (size_t)j * 4) = v;
    uint2 p;
    p.x = (u32)f2bf(v.x) | ((u32)f2bf(v.y) << 16);
    p.y = (u32)f2bf(v.z) | ((u32)f2bf(v.w) << 16);
    *(uint2*)(hb + (size_t)j * 4) = p;
  }
}

// ---------------- bf16 graph aggregation (mean over in-neighbors) ----------------
// one wave per node, 1 u32 (2 bf16) per lane; 4x edge unroll for MLP.
// NS=2: second source gathered with the same indices (8 loads in flight).
template <int NS>
__global__ __launch_bounds__(256) void aggb_kernel(const int* __restrict__ offs,
                                                   const int* __restrict__ csr,
                                                   const float* __restrict__ dinv,
                                                   const u16* __restrict__ s0,
                                                   const u16* __restrict__ s1,
                                                   u16* __restrict__ o0,
                                                   u16* __restrict__ o1, int N) {
  int wid = (blockIdx.x * 256 + threadIdx.x) >> 6;
  if (wid >= N) return;
  int lane = threadIdx.x & 63;
  size_t toff = (size_t)blockIdx.y * N * 64;       // u32 units
  int e0 = offs[wid], e1 = offs[wid + 1];
  float di = dinv[wid];
  const u32* S0 = (const u32*)s0 + toff;
  const u32* S1 = (const u32*)s1 + toff;
  float x0 = 0.f, y0 = 0.f, x0b = 0.f, y0b = 0.f;
  float x1 = 0.f, y1 = 0.f, x1b = 0.f, y1b = 0.f;
  int e = e0;
  for (; e + 4 <= e1; e += 4) {
    int j0 = csr[e]     * 64 + lane;
    int j1 = csr[e + 1] * 64 + lane;
    int j2 = csr[e + 2] * 64 + lane;
    int j3 = csr[e + 3] * 64 + lane;
    u32 v0 = S0[j0], v1 = S0[j1], v2 = S0[j2], v3 = S0[j3];
    u32 w0, w1, w2, w3;
    if constexpr (NS > 1) { w0 = S1[j0]; w1 = S1[j1]; w2 = S1[j2]; w3 = S1[j3]; }
    x0  += bf2f((u16)v0) + bf2f((u16)v1);
    y0  += bf2f((u16)(v0 >> 16)) + bf2f((u16)(v1 >> 16));
    x0b += bf2f((u16)v2) + bf2f((u16)v3);
    y0b += bf2f((u16)(v2 >> 16)) + bf2f((u16)(v3 >> 16));
    if constexpr (NS > 1) {
      x1  += bf2f((u16)w0) + bf2f((u16)w1);
      y1  += bf2f((u16)(w0 >> 16)) + bf2f((u16)(w1 >> 16));
      x1b += bf2f((u16)w2) + bf2f((u16)w3);
      y1b += bf2f((u16)(w2 >> 16)) + bf2f((u16)(w3 >> 16));
    }
  }
  for (; e < e1; ++e) {
    int j = csr[e] * 64 + lane;
    u32 v = S0[j];
    x0 += bf2f((u16)v); y0 += bf2f((u16)(v >> 16));
    if constexpr (NS > 1) {
      u32 w = S1[j];
      x1 += bf2f((u16)w); y1 += bf2f((u16)(w >> 16));
    }
  }
  int oidx = wid * 64 + lane;
  float sa0 = (x0 + x0b) * di, sb0 = (y0 + y0b) * di;
  ((u32*)o0)[toff + oidx] = (u32)f2bf(sa0) | ((u32)f2bf(sb0) << 16);
  if constexpr (NS > 1) {
    float sa1 = (x1 + x1b) * di, sb1 = (y1 + y1b) * di;
    ((u32*)o1)[toff + oidx] = (u32)f2bf(sa1) | ((u32)f2bf(sb1) << 16);
  }
}

// ---------------- unified GEMM kernel ----------------
// tile 64 rows x 256 cols, 512 threads (8 waves: wr=w&3 row band, wc=w>>2 u/c col half)
// MODE 0: pre  — batched over blockIdx.y=t, A=[xb_t|axb_t] (NKC=4, k 0:256), store P
// MODE 1: cell0 — A=[h0b|ah0b] (NKC=4, W pre-offset to k 256:512), acc init from P,
//                 epilogue u/c -> h update (fp32 + bf16 shadow)
// MODE 2: cell1 — A=[h0b|ah0nb|h1b|ah1b] (NKC=8), h update + fused out GEMM
template <int MODE, int NKC>
__global__ __launch_bounds__(512) void mm_kernel(const u16* __restrict__ s0,
                                                 const u16* __restrict__ s1,
                                                 const u16* __restrict__ s2,
                                                 const u16* __restrict__ s3,
                                                 const u16* __restrict__ W,
                                                 const float* __restrict__ bias,
                                                 float* __restrict__ P,
                                                 float* __restrict__ h,
                                                 u16* __restrict__ hb,
                                                 const u16* __restrict__ WoT,
                                                 const float* __restrict__ bout,
                                                 float* __restrict__ outp, int N) {
  __shared__ __align__(16) char smem[40960];
  u16* As = (u16*)smem;              // 64x64 bf16, swizzled (8KB)
  u16* Bs = (u16*)(smem + 8192);     // 256x64 bf16, swizzled (32KB)
  const u16* srcs[4] = {s0, s1, s2, s3};
  int tid = threadIdx.x, lane = tid & 63, w = tid >> 6;
  int wr = w & 3, wc = w >> 2;
  int row0 = blockIdx.x * 64;
  size_t soff = 0;
  if constexpr (MODE == 0) {
    soff = (size_t)blockIdx.y * N * DD;
    P += (size_t)blockIdx.y * N * 256;
  }

  f32x4 accU[4], accC[4];
  if constexpr (MODE == 1) {
    #pragma unroll
    for (int n = 0; n < 4; ++n) {
      int col = wc * 64 + n * 16 + (lane & 15);
      #pragma unroll
      for (int r = 0; r < 4; ++r) {
        int row = row0 + wr * 16 + (lane >> 4) * 4 + r;
        accU[n][r] = (row < N) ? P[(size_t)row * 256 + col] : 0.f;
        accC[n][r] = (row < N) ? P[(size_t)row * 256 + col + 128] : 0.f;
      }
    }
  } else {
    #pragma unroll
    for (int n = 0; n < 4; ++n) { accU[n] = (f32x4){0,0,0,0}; accC[n] = (f32x4){0,0,0,0}; }
  }

  #pragma unroll
  for (int kc = 0; kc < NKC; ++kc) {
    // ---- stage A (64x64 bf16, XOR-swizzled) ----
    {
      int r = tid >> 3, k8 = (tid & 7) * 8;
      const u16* sp = srcs[kc >> 1] + soff;
      int grow = row0 + r;
      uint4 v = make_uint4(0, 0, 0, 0);
      if (grow < N) v = *(const uint4*)(sp + (size_t)grow * DD + (kc & 1) * 64 + k8);
      int byte = (r * 128 + (tid & 7) * 16) ^ ((r & 7) << 4);
      *(uint4*)((char*)As + byte) = v;
    }
    // ---- stage B (256x64 bf16, XOR-swizzled) ----
    #pragma unroll
    for (int it = 0; it < 4; ++it) {
      int id = it * 512 + tid;
      int c = id >> 3, k8 = (id & 7) * 8;
      uint4 v = *(const uint4*)(W + c * 512 + kc * 64 + k8);
      int byte = (c * 128 + (id & 7) * 16) ^ ((c & 7) << 4);
      *(uint4*)((char*)Bs + byte) = v;
    }
    __syncthreads();
    #pragma unroll
    for (int ks = 0; ks < 2; ++ks) {
      int arow = wr * 16 + (lane & 15);
      int abyte = (arow * 128 + ks * 64 + (lane >> 4) * 16) ^ ((arow & 7) << 4);
      s16x8 af = *(const s16x8*)((char*)As + abyte);
      #pragma unroll
      for (int n = 0; n < 4; ++n) {
        int cu = wc * 64 + n * 16 + (lane & 15);
        int bub = (cu * 128 + ks * 64 + (lane >> 4) * 16) ^ ((cu & 7) << 4);
        s16x8 bu = *(const s16x8*)((char*)Bs + bub);
        accU[n] = __builtin_amdgcn_mfma_f32_16x16x32_bf16(af, bu, accU[n], 0, 0, 0);
        int cc = cu + 128;
        int bcb = (cc * 128 + ks * 64 + (lane >> 4) * 16) ^ ((cc & 7) << 4);
        s16x8 bc = *(const s16x8*)((char*)Bs + bcb);
        accC[n] = __builtin_amdgcn_mfma_f32_16x16x32_bf16(af, bc, accC[n], 0, 0, 0);
      }
    }
    __syncthreads();
  }

  if constexpr (MODE == 0) {
    #pragma unroll
    for (int n = 0; n < 4; ++n) {
      int col = wc * 64 + n * 16 + (lane & 15);
      #pragma unroll
      for (int r = 0; r < 4; ++r) {
        int row = row0 + wr * 16 + (lane >> 4) * 4 + r;
        if (row < N) {
          P[(size_t)row * 256 + col] = accU[n][r];
          P[(size_t)row * 256 + col + 128] = accC[n][r];
        }
      }
    }
  } else {
    // ---- epilogue: u=sigmoid, c=tanh, h' = u*h + (1-u)*c ----
    #pragma unroll
    for (int n = 0; n < 4; ++n) {
      int col = wc * 64 + n * 16 + (lane & 15);
      float bu = bias[col], bc = bias[128 + col];
      #pragma unroll
      for (int r = 0; r < 4; ++r) {
        int row = row0 + wr * 16 + (lane >> 4) * 4 + r;
        if (row < N) {
          float u = 1.0f / (1.0f + __expf(-(accU[n][r] + bu)));
          float cg = tanhf(accC[n][r] + bc);
          size_t idx = (size_t)row * DD + col;
          float hn = u * h[idx] + (1.0f - u) * cg;
          h[idx] = hn;
          u16 hnb = f2bf(hn);
          hb[idx] = hnb;
          if constexpr (MODE == 2) {
            int rl = row - row0;
            int hbyte = (rl * 256 + col * 2) ^ ((rl & 7) << 4);
            *(u16*)(smem + hbyte) = hnb;       // Hs overlays As/Bs (dead now)
          }
        }
      }
    }
    if constexpr (MODE == 2) {
      // stage WoT [64 cols][128 k] swizzled at smem+16384
      #pragma unroll
      for (int it = 0; it < 2; ++it) {
        int id = it * 512 + tid;
        int c = id >> 4, kc8 = (id & 15) * 8;
        uint4 v = *(const uint4*)(WoT + c * 128 + kc8);
        int byte = (c * 256 + kc8 * 2) ^ ((c & 7) << 4);
        *(uint4*)(smem + 16384 + byte) = v;
      }
      __syncthreads();
      f32x4 ao[2] = {};
      #pragma unroll
      for (int ks = 0; ks < 4; ++ks) {
        int arow = wr * 16 + (lane & 15);
        int abyte = (arow * 256 + ks * 64 + (lane >> 4) * 16) ^ ((arow & 7) << 4);
        s16x8 af = *(const s16x8*)(smem + abyte);
        #pragma unroll
        for (int n = 0; n < 2; ++n) {
          int co = wc * 32 + n * 16 + (lane & 15);
          int bbyte = (co * 256 + ks * 64 + (lane >> 4) * 16) ^ ((co & 7) << 4);
          s16x8 bf = *(const s16x8*)(smem + 16384 + bbyte);
          ao[n] = __builtin_amdgcn_mfma_f32_16x16x32_bf16(af, bf, ao[n], 0, 0, 0);
        }
      }
      #pragma unroll
      for (int n = 0; n < 2; ++n) {
        int co = wc * 32 + n * 16 + (lane & 15);
        float bb = bout[co];
        #pragma unroll
        for (int r = 0; r < 4; ++r) {
          int row = row0 + wr * 16 + (lane >> 4) * 4 + r;
          if (row < N) outp[(size_t)row * OO + co] = ao[n][r] + bb;
        }
      }
    }
  }
}

extern "C" void kernel_launch(void* const* d_in, const int* in_sizes, int n_in,
                              void* d_out, int out_size, void* d_ws, size_t ws_size,
                              hipStream_t stream) {
  const float* x      = (const float*)d_in[0];  // [T,N,D]
  const float* hs     = (const float*)d_in[1];  // [L,N,D]
  const float* Wself  = (const float*)d_in[2];  // [L,6,D,D]
  const float* Wneigh = (const float*)d_in[3];
  const float* b      = (const float*)d_in[4];  // [L,6,D]
  const float* Wout   = (const float*)d_in[5];  // [D,OUT]
  const float* bout   = (const float*)d_in[6];  // [OUT]
  const int*   src    = (const int*)d_in[7];    // [E]
  const int*   dst    = (const int*)d_in[8];    // [E]
  float* out = (float*)d_out;

  const int N = NN, E = EE, D = DD, T = TT;

  char* ws = (char*)d_ws;
  size_t off = 0;
  auto alloc = [&](size_t bytes) -> void* {
    void* p = ws + off;
    off = (off + bytes + 255) & ~(size_t)255;
    return p;
  };
  int*   deg     = (int*)alloc(N * 4);
  int*   offs    = (int*)alloc((N + 1) * 4);
  int*   cursor  = (int*)alloc(N * 4);
  int*   csr     = (int*)alloc(E * 4);
  float* dinv    = (float*)alloc(N * 4);
  u16*   Wp      = (u16*)alloc(2 * 256 * 512 * 2);
  float* biasbuf = (float*)alloc(512 * 4);
  u16*   WoT     = (u16*)alloc(64 * 128 * 2);
  float* hstate  = (float*)alloc((size_t)2 * N * D * 4);   // [2][N][D] fp32 state
  u16*   hb      = (u16*)alloc((size_t)2 * N * D * 2);     // bf16 shadow
  u16*   ah0b    = (u16*)alloc((size_t)N * D * 2);
  u16*   ah1b    = (u16*)alloc((size_t)N * D * 2);
  u16*   xb      = (u16*)alloc((size_t)T * N * D * 2);
  u16*   axb     = (u16*)alloc((size_t)T * N * D * 2);
  float* P       = (float*)alloc((size_t)T * N * 256 * 4);

  float* h0  = hstate;
  float* h1  = hstate + (size_t)N * D;
  u16*   h0b = hb;
  u16*   h1b = hb + (size_t)N * D;

  hipMemsetAsync(deg, 0, N * 4, stream);
  hipMemsetAsync(cursor, 0, N * 4, stream);
  count_kernel<<<(E + 255) / 256, 256, 0, stream>>>(dst, deg, E);
  scan_kernel<<<1, 1024, 0, stream>>>(deg, offs, dinv, N);
  fill_kernel<<<(E + 255) / 256, 256, 0, stream>>>(src, dst, offs, cursor, csr, E);
  {
    int tot = 2 * 256 * 512 + 64 * 128 + 512;
    pack_kernel<<<(tot + 255) / 256, 256, 0, stream>>>(Wself, Wneigh, b, Wout, Wp, biasbuf, WoT);
  }
  {
    int nx4 = T * N * D / 4, nh4 = 2 * N * D / 4;
    cvt_kernel<<<(nx4 + nh4 + 255) / 256, 256, 0, stream>>>(x, hs, xb, hstate, hb, nx4, nh4);
  }

  int aggGrid  = (N * 64 + 255) / 256;   // 2500 blocks, 1 node/wave
  int mmGrid   = (N + 63) / 64;          // 157

  // agg(x_t) for all t, batched over grid.y
  aggb_kernel<1><<<dim3(aggGrid, T), 256, 0, stream>>>(offs, csr, dinv, xb, xb, axb, axb, N);
  // P[t] = [xb_t | axb_t] @ W_layer0[k 0:256], batched over grid.y
  mm_kernel<0, 4><<<dim3(mmGrid, T), 512, 0, stream>>>(xb, axb, xb, xb, Wp, biasbuf, P,
                                                       nullptr, nullptr, nullptr, nullptr,
                                                       nullptr, N);
  // initial agg(h0_init) — agg(h1_init) would be dead (recomputed before first use)
  aggb_kernel<1><<<aggGrid, 256, 0, stream>>>(offs, csr, dinv, h0b, h0b, ah0b, ah0b, N);

  for (int t = 0; t < T; ++t) {
    // layer 0: h0 <- cell(x_t-part precomputed in P, h0, ah0)
    mm_kernel<1, 4><<<mmGrid, 512, 0, stream>>>(h0b, ah0b, h0b, h0b,
                                                Wp + 256, biasbuf,
                                                P + (size_t)t * N * 256,
                                                h0, h0b, nullptr, nullptr, nullptr, N);
    // merged dual agg: agg(h0'(t)) [cell1(t) + cell0(t+1)] and agg(h1'(t-1)) [cell1(t)]
    aggb_kernel<2><<<aggGrid, 256, 0, stream>>>(offs, csr, dinv, h0b, h1b, ah0b, ah1b, N);
    // layer 1 + fused out GEMM
    mm_kernel<2, 8><<<mmGrid, 512, 0, stream>>>(h0b, ah0b, h1b, ah1b,
                                                Wp + 131072, biasbuf + 256, nullptr,
                                                h1, h1b, WoT, bout,
                                                out + (size_t)t * N * OO, N);
  }
  // hidden_final = hstate [2][N][D]
  hipMemcpyAsync(out + (size_t)T * N * OO, hstate, (size_t)2 * N * D * 4,
                 hipMemcpyDeviceToDevice, stream);
}

// Round 4
// 735.873 us; speedup vs baseline: 2.3869x; 1.2220x over previous
//
#include <hip/hip_runtime.h>

typedef unsigned short u16;
typedef unsigned int   u32;
typedef __attribute__((ext_vector_type(4))) float f32x4;
typedef __attribute__((ext_vector_type(8))) short s16x8;

#define TT 12
#define NN 10000
#define EE 160000
#define DD 128
#define OO 64

__device__ __forceinline__ u16 f2bf(float f) {
  union { float f; u32 u; } x; x.f = f;
  u32 r = x.u + 0x7FFFu + ((x.u >> 16) & 1u);   // RNE
  return (u16)(r >> 16);
}
__device__ __forceinline__ float bf2f(u16 v) {
  union { u32 u; float f; } x; x.u = (u32)v << 16; return x.f;
}

// ---------------- CSR build ----------------
__global__ __launch_bounds__(256) void count_kernel(const int* __restrict__ dst,
                                                    int* __restrict__ deg, int E) {
  int e = blockIdx.x * 256 + threadIdx.x;
  if (e < E) atomicAdd(&deg[dst[e]], 1);
}

__global__ __launch_bounds__(1024) void scan_kernel(const int* __restrict__ deg,
                                                    int* __restrict__ offs,
                                                    float* __restrict__ dinv, int n) {
  __shared__ int buf[1024];
  __shared__ int carry_s;
  int tid = threadIdx.x;
  if (tid == 0) carry_s = 0;
  __syncthreads();
  for (int base = 0; base < n; base += 1024) {
    int v = (base + tid < n) ? deg[base + tid] : 0;
    buf[tid] = v;
    __syncthreads();
    for (int off = 1; off < 1024; off <<= 1) {
      int t = (tid >= off) ? buf[tid - off] : 0;
      __syncthreads();
      buf[tid] += t;
      __syncthreads();
    }
    int carry = carry_s;
    if (base + tid < n) {
      offs[base + tid] = carry + buf[tid] - v;          // exclusive
      dinv[base + tid] = (v > 0) ? 1.0f / (float)v : 0.0f;
    }
    __syncthreads();
    if (tid == 1023) carry_s = carry + buf[1023];
    __syncthreads();
  }
  if (tid == 0) offs[n] = carry_s;
}

__global__ __launch_bounds__(256) void fill_kernel(const int* __restrict__ src,
                                                   const int* __restrict__ dst,
                                                   const int* __restrict__ offs,
                                                   int* __restrict__ cursor,
                                                   int* __restrict__ csr, int E) {
  int e = blockIdx.x * 256 + threadIdx.x;
  if (e >= E) return;
  int d = dst[e];
  int pos = atomicAdd(&cursor[d], 1);
  csr[offs[d] + pos] = src[e];
}

// ---------------- weight/bias packing ----------------
__global__ __launch_bounds__(256) void pack_kernel(const float* __restrict__ Wself,
                                                   const float* __restrict__ Wneigh,
                                                   const float* __restrict__ b,
                                                   const float* __restrict__ Wout,
                                                   u16* __restrict__ Wp,
                                                   float* __restrict__ biasbuf,
                                                   u16* __restrict__ WoT) {
  int gid = blockIdx.x * 256 + threadIdx.x;
  const int NWP = 2 * 256 * 512;
  if (gid < NWP) {
    int j = gid >> 17;
    int rem = gid & 131071;
    int c = rem >> 9;
    int k = rem & 511;
    int seg = k >> 7, kd = k & 127;
    int cc = c & 127;
    int gate = (c < 128) ? (seg < 2 ? 2 : 3) : (seg < 2 ? 4 : 5);
    const float* M = (seg & 1) ? Wneigh : Wself;
    float v = M[((j * 6 + gate) * 128 + kd) * 128 + cc];
    Wp[gid] = f2bf(v);
  } else if (gid < NWP + 64 * 128) {
    int i = gid - NWP;
    int c = i >> 7, k = i & 127;                 // WoT[c][k] = Wout[k][c]
    WoT[i] = f2bf(Wout[k * OO + c]);
  } else if (gid < NWP + 64 * 128 + 512) {
    int i = gid - NWP - 64 * 128;
    int j = i >> 8, g = (i >> 7) & 1, d = i & 127;
    int g1 = g ? 4 : 2, g2 = g ? 5 : 3;
    biasbuf[i] = b[(j * 6 + g1) * 128 + d] + b[(j * 6 + g2) * 128 + d];
  }
}

// ---------------- convert: x -> xb (bf16), hs -> fp32 state + bf16 shadow ----------------
__global__ __launch_bounds__(256) void cvt_kernel(const float* __restrict__ x,
                                                  const float* __restrict__ hs,
                                                  u16* __restrict__ xb,
                                                  float* __restrict__ h0f,
                                                  u16* __restrict__ hb0,
                                                  float* __restrict__ h1f,
                                                  u16* __restrict__ hb1,
                                                  int nx4, int nh4half) {
  int i = blockIdx.x * 256 + threadIdx.x;
  if (i < nx4) {
    float4 v = *(const float4*)(x + (size_t)i * 4);
    uint2 p;
    p.x = (u32)f2bf(v.x) | ((u32)f2bf(v.y) << 16);
    p.y = (u32)f2bf(v.z) | ((u32)f2bf(v.w) << 16);
    *(uint2*)(xb + (size_t)i * 4) = p;
  } else if (i < nx4 + 2 * nh4half) {
    int j = i - nx4;
    int half = (j >= nh4half);
    int jj = half ? j - nh4half : j;
    float4 v = ((const float4*)hs)[j];
    float* fdst = half ? h1f : h0f;
    u16*   bdst = half ? hb1 : hb0;
    ((float4*)fdst)[jj] = v;
    uint2 p;
    p.x = (u32)f2bf(v.x) | ((u32)f2bf(v.y) << 16);
    p.y = (u32)f2bf(v.z) | ((u32)f2bf(v.w) << 16);
    ((uint2*)bdst)[jj] = p;
  }
}

// ---------------- gather-mean core: one wave = one node, one source ----------------
__device__ __forceinline__ void agg_one(const int* __restrict__ offs,
                                        const int* __restrict__ csr,
                                        const float* __restrict__ dinv,
                                        const u32* __restrict__ S,
                                        u32* __restrict__ O,
                                        int node, int lane) {
  int nu = __builtin_amdgcn_readfirstlane(node);   // wave-uniform -> scalar loads
  int e0 = offs[nu], e1 = offs[nu + 1];
  float di = dinv[nu];
  float xa = 0.f, ya = 0.f, xb_ = 0.f, yb_ = 0.f;
  int e = e0;
  for (; e + 4 <= e1; e += 4) {
    int i0 = csr[e], i1 = csr[e + 1], i2 = csr[e + 2], i3 = csr[e + 3];
    u32 v0 = S[i0 * 64 + lane];
    u32 v1 = S[i1 * 64 + lane];
    u32 v2 = S[i2 * 64 + lane];
    u32 v3 = S[i3 * 64 + lane];
    xa  += bf2f((u16)v0) + bf2f((u16)v1);
    ya  += bf2f((u16)(v0 >> 16)) + bf2f((u16)(v1 >> 16));
    xb_ += bf2f((u16)v2) + bf2f((u16)v3);
    yb_ += bf2f((u16)(v2 >> 16)) + bf2f((u16)(v3 >> 16));
  }
  for (; e < e1; ++e) {
    u32 v = S[csr[e] * 64 + lane];
    xa += bf2f((u16)v); ya += bf2f((u16)(v >> 16));
  }
  float sx = (xa + xb_) * di, sy = (ya + yb_) * di;
  O[nu * 64 + lane] = (u32)f2bf(sx) | ((u32)f2bf(sy) << 16);
}

// single-source agg, batched over blockIdx.y ([y][N][128] bf16)
__global__ __launch_bounds__(256) void aggs_kernel(const int* __restrict__ offs,
                                                   const int* __restrict__ csr,
                                                   const float* __restrict__ dinv,
                                                   const u16* __restrict__ s,
                                                   u16* __restrict__ o, int N) {
  int node = blockIdx.x * 4 + (threadIdx.x >> 6);
  if (node >= N) return;
  size_t yo = (size_t)blockIdx.y * N * 64;
  agg_one(offs, csr, dinv, (const u32*)s + yo, (u32*)o + yo, node, threadIdx.x & 63);
}

// dual agg, XCD-sharded: blockIdx&7 = XCD slot; XCD 0-3 -> source0, 4-7 -> source1.
// Each XCD's gather working set = one 2.56MB source (fits 4MiB L2). grid = 2 * (N/4).
__global__ __launch_bounds__(256) void aggdual_kernel(const int* __restrict__ offs,
                                                      const int* __restrict__ csr,
                                                      const float* __restrict__ dinv,
                                                      const u16* __restrict__ s0,
                                                      const u16* __restrict__ s1,
                                                      u16* __restrict__ o0,
                                                      u16* __restrict__ o1, int N) {
  int b = blockIdx.x;
  int srcsel = (b >> 2) & 1;
  int idx = (b >> 3) * 4 + (b & 3);
  int node = idx * 4 + (threadIdx.x >> 6);
  if (node >= N) return;
  const u32* S = (const u32*)(srcsel ? s1 : s0);
  u32* O = (u32*)(srcsel ? o1 : o0);
  agg_one(offs, csr, dinv, S, O, node, threadIdx.x & 63);
}

// ---------------- cell/GEMM body ----------------
// tile 64 rows x 256 cols, 512 threads (8 waves: wr=w&3 row band, wc=w>>2 col half)
// MODE 0: pre   — A=[s0|s1] (K=256), store raw acc to P
// MODE 1: cell0 — A=[s0|s1] (K=256, W pre-offset), acc init from P, h-update epilogue
// MODE 2: cell1 — A=[s0|s1|s2|s3] (K=512), h-update + fused out GEMM
template <int MODE>
__device__ __forceinline__ void cell_body(char* __restrict__ smem, int row0, int tid,
    const u16* __restrict__ s0, const u16* __restrict__ s1,
    const u16* __restrict__ s2, const u16* __restrict__ s3,
    const u16* __restrict__ W, const float* __restrict__ bias,
    float* __restrict__ P,
    const float* __restrict__ hin, float* __restrict__ hout, u16* __restrict__ hbout,
    const u16* __restrict__ WoT, const float* __restrict__ bout,
    float* __restrict__ outp, int N) {
  constexpr int NKC = (MODE == 2) ? 8 : 4;
  u16* As = (u16*)smem;              // 64x64 bf16 swizzled (8KB)
  u16* Bs = (u16*)(smem + 8192);     // 256x64 bf16 swizzled (32KB)
  const u16* srcs[4] = {s0, s1, s2, s3};
  int lane = tid & 63, w = tid >> 6;
  int wr = w & 3, wc = w >> 2;

  f32x4 accU[4], accC[4];
  if constexpr (MODE == 1) {
    #pragma unroll
    for (int n = 0; n < 4; ++n) {
      int col = wc * 64 + n * 16 + (lane & 15);
      #pragma unroll
      for (int r = 0; r < 4; ++r) {
        int row = row0 + wr * 16 + (lane >> 4) * 4 + r;
        accU[n][r] = (row < N) ? P[(size_t)row * 256 + col] : 0.f;
        accC[n][r] = (row < N) ? P[(size_t)row * 256 + col + 128] : 0.f;
      }
    }
  } else {
    #pragma unroll
    for (int n = 0; n < 4; ++n) { accU[n] = (f32x4){0,0,0,0}; accC[n] = (f32x4){0,0,0,0}; }
  }

  #pragma unroll
  for (int kc = 0; kc < NKC; ++kc) {
    {
      int r = tid >> 3, k8 = (tid & 7) * 8;
      const u16* sp = srcs[kc >> 1];
      int grow = row0 + r;
      uint4 v = make_uint4(0, 0, 0, 0);
      if (grow < N) v = *(const uint4*)(sp + (size_t)grow * DD + (kc & 1) * 64 + k8);
      int byte = (r * 128 + (tid & 7) * 16) ^ ((r & 7) << 4);
      *(uint4*)((char*)As + byte) = v;
    }
    #pragma unroll
    for (int it = 0; it < 4; ++it) {
      int id = it * 512 + tid;
      int c = id >> 3, k8 = (id & 7) * 8;
      uint4 v = *(const uint4*)(W + c * 512 + kc * 64 + k8);
      int byte = (c * 128 + (id & 7) * 16) ^ ((c & 7) << 4);
      *(uint4*)((char*)Bs + byte) = v;
    }
    __syncthreads();
    #pragma unroll
    for (int ks = 0; ks < 2; ++ks) {
      int arow = wr * 16 + (lane & 15);
      int abyte = (arow * 128 + ks * 64 + (lane >> 4) * 16) ^ ((arow & 7) << 4);
      s16x8 af = *(const s16x8*)((char*)As + abyte);
      #pragma unroll
      for (int n = 0; n < 4; ++n) {
        int cu = wc * 64 + n * 16 + (lane & 15);
        int bub = (cu * 128 + ks * 64 + (lane >> 4) * 16) ^ ((cu & 7) << 4);
        s16x8 bu = *(const s16x8*)((char*)Bs + bub);
        accU[n] = __builtin_amdgcn_mfma_f32_16x16x32_bf16(af, bu, accU[n], 0, 0, 0);
        int cc = cu + 128;
        int bcb = (cc * 128 + ks * 64 + (lane >> 4) * 16) ^ ((cc & 7) << 4);
        s16x8 bc = *(const s16x8*)((char*)Bs + bcb);
        accC[n] = __builtin_amdgcn_mfma_f32_16x16x32_bf16(af, bc, accC[n], 0, 0, 0);
      }
    }
    __syncthreads();
  }

  if constexpr (MODE == 0) {
    #pragma unroll
    for (int n = 0; n < 4; ++n) {
      int col = wc * 64 + n * 16 + (lane & 15);
      #pragma unroll
      for (int r = 0; r < 4; ++r) {
        int row = row0 + wr * 16 + (lane >> 4) * 4 + r;
        if (row < N) {
          P[(size_t)row * 256 + col] = accU[n][r];
          P[(size_t)row * 256 + col + 128] = accC[n][r];
        }
      }
    }
  } else {
    #pragma unroll
    for (int n = 0; n < 4; ++n) {
      int col = wc * 64 + n * 16 + (lane & 15);
      float bu = bias[col], bc = bias[128 + col];
      #pragma unroll
      for (int r = 0; r < 4; ++r) {
        int row = row0 + wr * 16 + (lane >> 4) * 4 + r;
        if (row < N) {
          float u = 1.0f / (1.0f + __expf(-(accU[n][r] + bu)));
          float cg = tanhf(accC[n][r] + bc);
          size_t idx = (size_t)row * DD + col;
          float hn = u * hin[idx] + (1.0f - u) * cg;
          hout[idx] = hn;
          u16 hnb = f2bf(hn);
          hbout[idx] = hnb;
          if constexpr (MODE == 2) {
            int rl = row - row0;
            int hbyte = (rl * 256 + col * 2) ^ ((rl & 7) << 4);
            *(u16*)(smem + hbyte) = hnb;       // h1' tile overlays As/Bs (dead now)
          }
        }
      }
    }
    if constexpr (MODE == 2) {
      #pragma unroll
      for (int it = 0; it < 2; ++it) {
        int id = it * 512 + tid;
        int c = id >> 4, kc8 = (id & 15) * 8;
        uint4 v = *(const uint4*)(WoT + c * 128 + kc8);
        int byte = (c * 256 + kc8 * 2) ^ ((c & 7) << 4);
        *(uint4*)(smem + 16384 + byte) = v;
      }
      __syncthreads();
      f32x4 ao[2] = {};
      #pragma unroll
      for (int ks = 0; ks < 4; ++ks) {
        int arow = wr * 16 + (lane & 15);
        int abyte = (arow * 256 + ks * 64 + (lane >> 4) * 16) ^ ((arow & 7) << 4);
        s16x8 af = *(const s16x8*)(smem + abyte);
        #pragma unroll
        for (int n = 0; n < 2; ++n) {
          int co = wc * 32 + n * 16 + (lane & 15);
          int bbyte = (co * 256 + ks * 64 + (lane >> 4) * 16) ^ ((co & 7) << 4);
          s16x8 bf = *(const s16x8*)(smem + 16384 + bbyte);
          ao[n] = __builtin_amdgcn_mfma_f32_16x16x32_bf16(af, bf, ao[n], 0, 0, 0);
        }
      }
      #pragma unroll
      for (int n = 0; n < 2; ++n) {
        int co = wc * 32 + n * 16 + (lane & 15);
        float bb = bout[co];
        #pragma unroll
        for (int r = 0; r < 4; ++r) {
          int row = row0 + wr * 16 + (lane >> 4) * 4 + r;
          if (row < N) outp[(size_t)row * OO + co] = ao[n][r] + bb;
        }
      }
    }
  }
}

// batched pre: P[t] = [xb_t | axb_t] @ W_layer0[k 0:256]
__global__ __launch_bounds__(512) void pre_kernel(const u16* __restrict__ xb,
                                                  const u16* __restrict__ axb,
                                                  const u16* __restrict__ Wp,
                                                  float* __restrict__ P, int N) {
  __shared__ __align__(16) char smem[40960];
  size_t yo = (size_t)blockIdx.y * N * DD;
  cell_body<0>(smem, blockIdx.x * 64, threadIdx.x, xb + yo, axb + yo, nullptr, nullptr,
               Wp, nullptr, P + (size_t)blockIdx.y * N * 256,
               nullptr, nullptr, nullptr, nullptr, nullptr, nullptr, N);
}

// standalone cell0 (t=0)
__global__ __launch_bounds__(512) void cell0_kernel(const u16* __restrict__ hb0c,
                                                    const u16* __restrict__ ah0,
                                                    const u16* __restrict__ W,
                                                    const float* __restrict__ bias,
                                                    float* __restrict__ Pt,
                                                    const float* __restrict__ h0in,
                                                    float* __restrict__ h0out,
                                                    u16* __restrict__ hb0out, int N) {
  __shared__ __align__(16) char smem[40960];
  cell_body<1>(smem, blockIdx.x * 64, threadIdx.x, hb0c, ah0, nullptr, nullptr,
               W, bias, Pt, h0in, h0out, hb0out, nullptr, nullptr, nullptr, N);
}

// merged step: even blocks = cell1(t)+out(t), odd blocks = cell0(t+1)
template <int WITHC0>
__global__ __launch_bounds__(512) void step_kernel(const u16* __restrict__ hb0c,
                                                   const u16* __restrict__ ah0,
                                                   const u16* __restrict__ hb1r,
                                                   const u16* __restrict__ ah1,
                                                   const u16* __restrict__ Wp,
                                                   const float* __restrict__ biasbuf,
                                                   float* __restrict__ Pn,
                                                   float* __restrict__ h1f,
                                                   u16* __restrict__ hb1w,
                                                   const float* __restrict__ h0in,
                                                   float* __restrict__ h0out,
                                                   u16* __restrict__ hb0out,
                                                   const u16* __restrict__ WoT,
                                                   const float* __restrict__ bout,
                                                   float* __restrict__ outp, int N) {
  __shared__ __align__(16) char smem[40960];
  int bx = blockIdx.x;
  int role = WITHC0 ? (bx & 1) : 0;
  int row0 = (WITHC0 ? (bx >> 1) : bx) * 64;
  if (role == 0) {
    cell_body<2>(smem, row0, threadIdx.x, hb0c, ah0, hb1r, ah1,
                 Wp + 131072, biasbuf + 256, nullptr,
                 h1f, h1f, hb1w, WoT, bout, outp, N);
  } else {
    cell_body<1>(smem, row0, threadIdx.x, hb0c, ah0, nullptr, nullptr,
                 Wp + 256, biasbuf, Pn,
                 h0in, h0out, hb0out, nullptr, nullptr, nullptr, N);
  }
}

extern "C" void kernel_launch(void* const* d_in, const int* in_sizes, int n_in,
                              void* d_out, int out_size, void* d_ws, size_t ws_size,
                              hipStream_t stream) {
  const float* x      = (const float*)d_in[0];  // [T,N,D]
  const float* hs     = (const float*)d_in[1];  // [L,N,D]
  const float* Wself  = (const float*)d_in[2];  // [L,6,D,D]
  const float* Wneigh = (const float*)d_in[3];
  const float* b      = (const float*)d_in[4];  // [L,6,D]
  const float* Wout   = (const float*)d_in[5];  // [D,OUT]
  const float* bout   = (const float*)d_in[6];  // [OUT]
  const int*   src    = (const int*)d_in[7];    // [E]
  const int*   dst    = (const int*)d_in[8];    // [E]
  float* out = (float*)d_out;

  const int N = NN, E = EE, D = DD, T = TT;

  char* ws = (char*)d_ws;
  size_t off = 0;
  auto alloc = [&](size_t bytes) -> void* {
    void* p = ws + off;
    off = (off + bytes + 255) & ~(size_t)255;
    return p;
  };
  int*   deg     = (int*)alloc(N * 4);
  int*   offs    = (int*)alloc((N + 1) * 4);
  int*   cursor  = (int*)alloc(N * 4);
  int*   csr     = (int*)alloc(E * 4);
  float* dinv    = (float*)alloc(N * 4);
  u16*   Wp      = (u16*)alloc(2 * 256 * 512 * 2);
  float* biasbuf = (float*)alloc(512 * 4);
  u16*   WoT     = (u16*)alloc(64 * 128 * 2);
  float* h0A     = (float*)alloc((size_t)N * D * 4);
  float* h0B     = (float*)alloc((size_t)N * D * 4);
  float* h1f     = (float*)alloc((size_t)N * D * 4);
  u16*   hb0A    = (u16*)alloc((size_t)N * D * 2);
  u16*   hb0B    = (u16*)alloc((size_t)N * D * 2);
  u16*   hb1     = (u16*)alloc((size_t)N * D * 2);
  u16*   ah0b    = (u16*)alloc((size_t)N * D * 2);
  u16*   ah1b    = (u16*)alloc((size_t)N * D * 2);
  u16*   xb      = (u16*)alloc((size_t)T * N * D * 2);
  u16*   axb     = (u16*)alloc((size_t)T * N * D * 2);
  float* P       = (float*)alloc((size_t)T * N * 256 * 4);

  float* h0f[2] = {h0A, h0B};
  u16*   hb0[2] = {hb0A, hb0B};

  hipMemsetAsync(deg, 0, N * 4, stream);
  hipMemsetAsync(cursor, 0, N * 4, stream);
  count_kernel<<<(E + 255) / 256, 256, 0, stream>>>(dst, deg, E);
  scan_kernel<<<1, 1024, 0, stream>>>(deg, offs, dinv, N);
  fill_kernel<<<(E + 255) / 256, 256, 0, stream>>>(src, dst, offs, cursor, csr, E);
  {
    int tot = 2 * 256 * 512 + 64 * 128 + 512;
    pack_kernel<<<(tot + 255) / 256, 256, 0, stream>>>(Wself, Wneigh, b, Wout, Wp, biasbuf, WoT);
  }
  {
    int nx4 = T * N * D / 4, nh4half = N * D / 4;
    cvt_kernel<<<(nx4 + 2 * nh4half + 255) / 256, 256, 0, stream>>>(
        x, hs, xb, h0A, hb0A, h1f, hb1, nx4, nh4half);
  }

  int aggGrid = (N + 3) / 4;   // 2500
  int mmGrid  = (N + 63) / 64; // 157

  // agg(x_t) for all t (batched), then P[t] for all t (batched)
  aggs_kernel<<<dim3(aggGrid, T), 256, 0, stream>>>(offs, csr, dinv, xb, axb, N);
  pre_kernel<<<dim3(mmGrid, T), 512, 0, stream>>>(xb, axb, Wp, P, N);
  // agg(h0_init) for cell0(0)
  aggs_kernel<<<aggGrid, 256, 0, stream>>>(offs, csr, dinv, hb0A, ah0b, N);
  // cell0(0): reads h0A, writes h0B
  cell0_kernel<<<mmGrid, 512, 0, stream>>>(hb0A, ah0b, Wp + 256, biasbuf, P,
                                           h0A, h0B, hb0B, N);

  for (int t = 0; t < T; ++t) {
    u16* cur = hb0[(t + 1) & 1];   // h0'(t) bf16
    // XCD-sharded dual agg: agg(h0'(t)) and agg(h1'(t-1) or h1_init)
    aggdual_kernel<<<2 * aggGrid, 256, 0, stream>>>(offs, csr, dinv, cur, hb1,
                                                    ah0b, ah1b, N);
    if (t < T - 1) {
      // cell1(t) (+out) merged with cell0(t+1) (ping-pong h0)
      step_kernel<1><<<2 * mmGrid, 512, 0, stream>>>(
          cur, ah0b, hb1, ah1b, Wp, biasbuf,
          P + (size_t)(t + 1) * N * 256,
          h1f, hb1,
          h0f[(t + 1) & 1], h0f[t & 1], hb0[t & 1],
          WoT, bout, out + (size_t)t * N * OO, N);
    } else {
      step_kernel<0><<<mmGrid, 512, 0, stream>>>(
          cur, ah0b, hb1, ah1b, Wp, biasbuf, nullptr,
          h1f, hb1, nullptr, nullptr, nullptr,
          WoT, bout, out + (size_t)t * N * OO, N);
    }
  }
  // hidden_final = [h0'(T-1), h1'(T-1)]; h0'(11) lives in h0f[0] (T=12, fixed parity)
  hipMemcpyAsync(out + (size_t)T * N * OO, h0f[0], (size_t)N * D * 4,
                 hipMemcpyDeviceToDevice, stream);
  hipMemcpyAsync(out + (size_t)T * N * OO + (size_t)N * D, h1f, (size_t)N * D * 4,
                 hipMemcpyDeviceToDevice, stream);
}

// Round 5
// 681.004 us; speedup vs baseline: 2.5792x; 1.0806x over previous
//
#include <hip/hip_runtime.h>

typedef unsigned short u16;
typedef unsigned int   u32;
typedef __attribute__((ext_vector_type(4))) float f32x4;
typedef __attribute__((ext_vector_type(8))) short s16x8;

#define TT 12
#define NN 10000
#define EE 160000
#define DD 128
#define OO 64

__device__ __forceinline__ u16 f2bf(float f) {
  union { float f; u32 u; } x; x.f = f;
  u32 r = x.u + 0x7FFFu + ((x.u >> 16) & 1u);   // RNE
  return (u16)(r >> 16);
}
__device__ __forceinline__ float bf2f(u16 v) {
  union { u32 u; float f; } x; x.u = (u32)v << 16; return x.f;
}

// ---------------- fused prep: cvt(x,hs) + count(deg) + pack(W,b,Wout) ----------------
__global__ __launch_bounds__(256) void prep_kernel(
    const float* __restrict__ x, const float* __restrict__ hs,
    const int* __restrict__ dst,
    const float* __restrict__ Wself, const float* __restrict__ Wneigh,
    const float* __restrict__ b, const float* __restrict__ Wout,
    u16* __restrict__ xb, float* __restrict__ h0f, u16* __restrict__ hb0,
    float* __restrict__ h1f, u16* __restrict__ hb1,
    int* __restrict__ deg, u16* __restrict__ Wp,
    float* __restrict__ biasbuf, u16* __restrict__ WoT,
    int nx4, int nh4half, int E) {
  int gid = blockIdx.x * 256 + threadIdx.x;
  const int NWP = 2 * 256 * 512;
  int cvtEnd  = nx4 + 2 * nh4half;
  int cntEnd  = cvtEnd + E;
  if (gid < nx4) {
    float4 v = *(const float4*)(x + (size_t)gid * 4);
    uint2 p;
    p.x = (u32)f2bf(v.x) | ((u32)f2bf(v.y) << 16);
    p.y = (u32)f2bf(v.z) | ((u32)f2bf(v.w) << 16);
    *(uint2*)(xb + (size_t)gid * 4) = p;
  } else if (gid < cvtEnd) {
    int j = gid - nx4;
    int half = (j >= nh4half);
    int jj = half ? j - nh4half : j;
    float4 v = ((const float4*)hs)[j];
    float* fdst = half ? h1f : h0f;
    u16*   bdst = half ? hb1 : hb0;
    ((float4*)fdst)[jj] = v;
    uint2 p;
    p.x = (u32)f2bf(v.x) | ((u32)f2bf(v.y) << 16);
    p.y = (u32)f2bf(v.z) | ((u32)f2bf(v.w) << 16);
    ((uint2*)bdst)[jj] = p;
  } else if (gid < cntEnd) {
    int e = gid - cvtEnd;
    atomicAdd(&deg[dst[e]], 1);
  } else {
    int pg = gid - cntEnd;
    if (pg < NWP) {
      int j = pg >> 17;
      int rem = pg & 131071;
      int c = rem >> 9;
      int k = rem & 511;
      int seg = k >> 7, kd = k & 127;
      int cc = c & 127;
      int gate = (c < 128) ? (seg < 2 ? 2 : 3) : (seg < 2 ? 4 : 5);
      const float* M = (seg & 1) ? Wneigh : Wself;
      float v = M[((j * 6 + gate) * 128 + kd) * 128 + cc];
      Wp[pg] = f2bf(v);
    } else if (pg < NWP + 64 * 128) {
      int i = pg - NWP;
      int c = i >> 7, k = i & 127;               // WoT[c][k] = Wout[k][c]
      WoT[i] = f2bf(Wout[k * OO + c]);
    } else if (pg < NWP + 64 * 128 + 512) {
      int i = pg - NWP - 64 * 128;
      int j = i >> 8, g = (i >> 7) & 1, d = i & 127;
      int g1 = g ? 4 : 2, g2 = g ? 5 : 3;
      biasbuf[i] = b[(j * 6 + g1) * 128 + d] + b[(j * 6 + g2) * 128 + d];
    }
  }
}

// ---------------- scan: single block, one barrier phase ----------------
__global__ __launch_bounds__(1024) void scan_kernel(const int* __restrict__ deg,
                                                    int* __restrict__ offs,
                                                    float* __restrict__ dinv, int n) {
  __shared__ int lds_deg[10240];
  __shared__ int wsum[16];
  int tid = threadIdx.x;
  for (int i = tid; i < 10240; i += 1024) lds_deg[i] = (i < n) ? deg[i] : 0;
  __syncthreads();
  int base = tid * 10;
  int loc[10];
  int s = 0;
  #pragma unroll
  for (int k = 0; k < 10; ++k) { loc[k] = s; s += lds_deg[base + k]; }
  int lane = tid & 63;
  int incl = s;
  #pragma unroll
  for (int d = 1; d < 64; d <<= 1) {
    int t2 = __shfl_up(incl, d);
    if (lane >= d) incl += t2;
  }
  int wid = tid >> 6;
  if (lane == 63) wsum[wid] = incl;
  __syncthreads();
  int wpre = 0;
  for (int k = 0; k < wid; ++k) wpre += wsum[k];
  int excl = wpre + incl - s;                      // exclusive prefix of this run
  #pragma unroll
  for (int k = 0; k < 10; ++k) {
    int idx = base + k;
    if (idx < n) {
      int d0 = lds_deg[idx];
      offs[idx] = excl + loc[k];
      dinv[idx] = (d0 > 0) ? 1.0f / (float)d0 : 0.0f;
    }
  }
  if (tid == 1023) offs[n] = excl + s;
}

__global__ __launch_bounds__(256) void fill_kernel(const int* __restrict__ src,
                                                   const int* __restrict__ dst,
                                                   const int* __restrict__ offs,
                                                   int* __restrict__ cursor,
                                                   int* __restrict__ csr, int E) {
  int e = blockIdx.x * 256 + threadIdx.x;
  if (e >= E) return;
  int d = dst[e];
  int pos = atomicAdd(&cursor[d], 1);
  csr[offs[d] + pos] = src[e] * 64;                // pre-scaled (u32 stride per node)
}

// ---------------- gather-mean core: one wave = one node; 8-deep MLP ----------------
__device__ __forceinline__ void agg_one(const int* __restrict__ offs,
                                        const int* __restrict__ csr,
                                        const float* __restrict__ dinv,
                                        const u32* __restrict__ S,
                                        u32* __restrict__ O,
                                        int node, int lane) {
  int nu = __builtin_amdgcn_readfirstlane(node);   // wave-uniform -> scalar loads
  int e0 = offs[nu], e1 = offs[nu + 1];
  float di = dinv[nu];
  float xa = 0.f, ya = 0.f, xb_ = 0.f, yb_ = 0.f;
  float xc = 0.f, yc = 0.f, xd = 0.f, yd = 0.f;
  int e = e0;
  for (; e + 8 <= e1; e += 8) {
    int i0 = csr[e],     i1 = csr[e + 1], i2 = csr[e + 2], i3 = csr[e + 3];
    int i4 = csr[e + 4], i5 = csr[e + 5], i6 = csr[e + 6], i7 = csr[e + 7];
    u32 v0 = S[i0 + lane], v1 = S[i1 + lane], v2 = S[i2 + lane], v3 = S[i3 + lane];
    u32 v4 = S[i4 + lane], v5 = S[i5 + lane], v6 = S[i6 + lane], v7 = S[i7 + lane];
    xa  += bf2f((u16)v0) + bf2f((u16)v1);
    ya  += bf2f((u16)(v0 >> 16)) + bf2f((u16)(v1 >> 16));
    xb_ += bf2f((u16)v2) + bf2f((u16)v3);
    yb_ += bf2f((u16)(v2 >> 16)) + bf2f((u16)(v3 >> 16));
    xc  += bf2f((u16)v4) + bf2f((u16)v5);
    yc  += bf2f((u16)(v4 >> 16)) + bf2f((u16)(v5 >> 16));
    xd  += bf2f((u16)v6) + bf2f((u16)v7);
    yd  += bf2f((u16)(v6 >> 16)) + bf2f((u16)(v7 >> 16));
  }
  for (; e + 4 <= e1; e += 4) {
    int i0 = csr[e], i1 = csr[e + 1], i2 = csr[e + 2], i3 = csr[e + 3];
    u32 v0 = S[i0 + lane], v1 = S[i1 + lane], v2 = S[i2 + lane], v3 = S[i3 + lane];
    xa  += bf2f((u16)v0) + bf2f((u16)v1);
    ya  += bf2f((u16)(v0 >> 16)) + bf2f((u16)(v1 >> 16));
    xb_ += bf2f((u16)v2) + bf2f((u16)v3);
    yb_ += bf2f((u16)(v2 >> 16)) + bf2f((u16)(v3 >> 16));
  }
  for (; e < e1; ++e) {
    u32 v = S[csr[e] + lane];
    xa += bf2f((u16)v); ya += bf2f((u16)(v >> 16));
  }
  float sx = ((xa + xb_) + (xc + xd)) * di;
  float sy = ((ya + yb_) + (yc + yd)) * di;
  O[nu * 64 + lane] = (u32)f2bf(sx) | ((u32)f2bf(sy) << 16);
}

// single-source agg (initial h0 agg)
__global__ __launch_bounds__(256) void aggs_kernel(const int* __restrict__ offs,
                                                   const int* __restrict__ csr,
                                                   const float* __restrict__ dinv,
                                                   const u16* __restrict__ s,
                                                   u16* __restrict__ o, int N) {
  int node = blockIdx.x * 4 + (threadIdx.x >> 6);
  if (node >= N) return;
  agg_one(offs, csr, dinv, (const u32*)s, (u32*)o, node, threadIdx.x & 63);
}

// x-agg, t-sharded by XCD slot: each XCD's gather source is ONE 2.56MB t-slice.
// grid = 30000: ids [0,20000) -> t = id&7; ids [20000,30000) -> 4 slices x 2 slots.
__global__ __launch_bounds__(256) void aggx_kernel(const int* __restrict__ offs,
                                                   const int* __restrict__ csr,
                                                   const float* __restrict__ dinv,
                                                   const u16* __restrict__ xb,
                                                   u16* __restrict__ axb, int N) {
  int id = blockIdx.x;
  int t, grp;
  if (id < 20000) {
    t = id & 7;
    grp = id >> 3;                               // [0,2500)
  } else {
    int j = id - 20000;                          // [0,10000)
    int slot = j & 7;
    t = 8 + (slot & 3);
    grp = (slot >> 2) * 1250 + (j >> 3);         // [0,2500)
  }
  int node = grp * 4 + (threadIdx.x >> 6);
  if (node >= N) return;
  size_t yo = (size_t)t * N * 64;
  agg_one(offs, csr, dinv, (const u32*)xb + yo, (u32*)axb + yo, node, threadIdx.x & 63);
}

// dual agg, XCD-sharded: XCD slots 0-3 -> source0, 4-7 -> source1.
__global__ __launch_bounds__(256) void aggdual_kernel(const int* __restrict__ offs,
                                                      const int* __restrict__ csr,
                                                      const float* __restrict__ dinv,
                                                      const u16* __restrict__ s0,
                                                      const u16* __restrict__ s1,
                                                      u16* __restrict__ o0,
                                                      u16* __restrict__ o1, int N) {
  int b = blockIdx.x;
  int srcsel = (b >> 2) & 1;
  int idx = (b >> 3) * 4 + (b & 3);
  int node = idx * 4 + (threadIdx.x >> 6);
  if (node >= N) return;
  const u32* S = (const u32*)(srcsel ? s1 : s0);
  u32* O = (u32*)(srcsel ? o1 : o0);
  agg_one(offs, csr, dinv, S, O, node, threadIdx.x & 63);
}

// ---------------- cell/GEMM body ----------------
// tile 64 rows x 256 cols, 512 threads (8 waves: wr=w&3 row band, wc=w>>2 col half)
// MODE 0: pre   — A=[s0|s1] (K=256), store raw acc to P
// MODE 1: cell0 — A=[s0|s1] (K=256, W pre-offset), acc init from P, h-update epilogue
// MODE 2: cell1 — A=[s0|s1|s2|s3] (K=512), h-update + fused out GEMM
template <int MODE>
__device__ __forceinline__ void cell_body(char* __restrict__ smem, int row0, int tid,
    const u16* __restrict__ s0, const u16* __restrict__ s1,
    const u16* __restrict__ s2, const u16* __restrict__ s3,
    const u16* __restrict__ W, const float* __restrict__ bias,
    float* __restrict__ P,
    const float* __restrict__ hin, float* __restrict__ hout, u16* __restrict__ hbout,
    const u16* __restrict__ WoT, const float* __restrict__ bout,
    float* __restrict__ outp, int N) {
  constexpr int NKC = (MODE == 2) ? 8 : 4;
  u16* As = (u16*)smem;              // 64x64 bf16 swizzled (8KB)
  u16* Bs = (u16*)(smem + 8192);     // 256x64 bf16 swizzled (32KB)
  const u16* srcs[4] = {s0, s1, s2, s3};
  int lane = tid & 63, w = tid >> 6;
  int wr = w & 3, wc = w >> 2;

  f32x4 accU[4], accC[4];
  if constexpr (MODE == 1) {
    #pragma unroll
    for (int n = 0; n < 4; ++n) {
      int col = wc * 64 + n * 16 + (lane & 15);
      #pragma unroll
      for (int r = 0; r < 4; ++r) {
        int row = row0 + wr * 16 + (lane >> 4) * 4 + r;
        accU[n][r] = (row < N) ? P[(size_t)row * 256 + col] : 0.f;
        accC[n][r] = (row < N) ? P[(size_t)row * 256 + col + 128] : 0.f;
      }
    }
  } else {
    #pragma unroll
    for (int n = 0; n < 4; ++n) { accU[n] = (f32x4){0,0,0,0}; accC[n] = (f32x4){0,0,0,0}; }
  }

  #pragma unroll
  for (int kc = 0; kc < NKC; ++kc) {
    {
      int r = tid >> 3, k8 = (tid & 7) * 8;
      const u16* sp = srcs[kc >> 1];
      int grow = row0 + r;
      uint4 v = make_uint4(0, 0, 0, 0);
      if (grow < N) v = *(const uint4*)(sp + (size_t)grow * DD + (kc & 1) * 64 + k8);
      int byte = (r * 128 + (tid & 7) * 16) ^ ((r & 7) << 4);
      *(uint4*)((char*)As + byte) = v;
    }
    #pragma unroll
    for (int it = 0; it < 4; ++it) {
      int id = it * 512 + tid;
      int c = id >> 3, k8 = (id & 7) * 8;
      uint4 v = *(const uint4*)(W + c * 512 + kc * 64 + k8);
      int byte = (c * 128 + (id & 7) * 16) ^ ((c & 7) << 4);
      *(uint4*)((char*)Bs + byte) = v;
    }
    __syncthreads();
    #pragma unroll
    for (int ks = 0; ks < 2; ++ks) {
      int arow = wr * 16 + (lane & 15);
      int abyte = (arow * 128 + ks * 64 + (lane >> 4) * 16) ^ ((arow & 7) << 4);
      s16x8 af = *(const s16x8*)((char*)As + abyte);
      #pragma unroll
      for (int n = 0; n < 4; ++n) {
        int cu = wc * 64 + n * 16 + (lane & 15);
        int bub = (cu * 128 + ks * 64 + (lane >> 4) * 16) ^ ((cu & 7) << 4);
        s16x8 bu = *(const s16x8*)((char*)Bs + bub);
        accU[n] = __builtin_amdgcn_mfma_f32_16x16x32_bf16(af, bu, accU[n], 0, 0, 0);
        int cc = cu + 128;
        int bcb = (cc * 128 + ks * 64 + (lane >> 4) * 16) ^ ((cc & 7) << 4);
        s16x8 bc = *(const s16x8*)((char*)Bs + bcb);
        accC[n] = __builtin_amdgcn_mfma_f32_16x16x32_bf16(af, bc, accC[n], 0, 0, 0);
      }
    }
    __syncthreads();
  }

  if constexpr (MODE == 0) {
    #pragma unroll
    for (int n = 0; n < 4; ++n) {
      int col = wc * 64 + n * 16 + (lane & 15);
      #pragma unroll
      for (int r = 0; r < 4; ++r) {
        int row = row0 + wr * 16 + (lane >> 4) * 4 + r;
        if (row < N) {
          P[(size_t)row * 256 + col] = accU[n][r];
          P[(size_t)row * 256 + col + 128] = accC[n][r];
        }
      }
    }
  } else {
    #pragma unroll
    for (int n = 0; n < 4; ++n) {
      int col = wc * 64 + n * 16 + (lane & 15);
      float bu = bias[col], bc = bias[128 + col];
      #pragma unroll
      for (int r = 0; r < 4; ++r) {
        int row = row0 + wr * 16 + (lane >> 4) * 4 + r;
        if (row < N) {
          float u = 1.0f / (1.0f + __expf(-(accU[n][r] + bu)));
          float cg = tanhf(accC[n][r] + bc);
          size_t idx = (size_t)row * DD + col;
          float hn = u * hin[idx] + (1.0f - u) * cg;
          hout[idx] = hn;
          u16 hnb = f2bf(hn);
          hbout[idx] = hnb;
          if constexpr (MODE == 2) {
            int rl = row - row0;
            int hbyte = (rl * 256 + col * 2) ^ ((rl & 7) << 4);
            *(u16*)(smem + hbyte) = hnb;       // h1' tile overlays As/Bs (dead now)
          }
        }
      }
    }
    if constexpr (MODE == 2) {
      #pragma unroll
      for (int it = 0; it < 2; ++it) {
        int id = it * 512 + tid;
        int c = id >> 4, kc8 = (id & 15) * 8;
        uint4 v = *(const uint4*)(WoT + c * 128 + kc8);
        int byte = (c * 256 + kc8 * 2) ^ ((c & 7) << 4);
        *(uint4*)(smem + 16384 + byte) = v;
      }
      __syncthreads();
      f32x4 ao[2] = {};
      #pragma unroll
      for (int ks = 0; ks < 4; ++ks) {
        int arow = wr * 16 + (lane & 15);
        int abyte = (arow * 256 + ks * 64 + (lane >> 4) * 16) ^ ((arow & 7) << 4);
        s16x8 af = *(const s16x8*)(smem + abyte);
        #pragma unroll
        for (int n = 0; n < 2; ++n) {
          int co = wc * 32 + n * 16 + (lane & 15);
          int bbyte = (co * 256 + ks * 64 + (lane >> 4) * 16) ^ ((co & 7) << 4);
          s16x8 bf = *(const s16x8*)(smem + 16384 + bbyte);
          ao[n] = __builtin_amdgcn_mfma_f32_16x16x32_bf16(af, bf, ao[n], 0, 0, 0);
        }
      }
      #pragma unroll
      for (int n = 0; n < 2; ++n) {
        int co = wc * 32 + n * 16 + (lane & 15);
        float bb = bout[co];
        #pragma unroll
        for (int r = 0; r < 4; ++r) {
          int row = row0 + wr * 16 + (lane >> 4) * 4 + r;
          if (row < N) outp[(size_t)row * OO + co] = ao[n][r] + bb;
        }
      }
    }
  }
}

// batched pre: P[t] = [xb_t | axb_t] @ W_layer0[k 0:256]
__global__ __launch_bounds__(512) void pre_kernel(const u16* __restrict__ xb,
                                                  const u16* __restrict__ axb,
                                                  const u16* __restrict__ Wp,
                                                  float* __restrict__ P, int N) {
  __shared__ __align__(16) char smem[40960];
  size_t yo = (size_t)blockIdx.y * N * DD;
  cell_body<0>(smem, blockIdx.x * 64, threadIdx.x, xb + yo, axb + yo, nullptr, nullptr,
               Wp, nullptr, P + (size_t)blockIdx.y * N * 256,
               nullptr, nullptr, nullptr, nullptr, nullptr, nullptr, N);
}

// standalone cell0 (t=0)
__global__ __launch_bounds__(512) void cell0_kernel(const u16* __restrict__ hb0c,
                                                    const u16* __restrict__ ah0,
                                                    const u16* __restrict__ W,
                                                    const float* __restrict__ bias,
                                                    float* __restrict__ Pt,
                                                    const float* __restrict__ h0in,
                                                    float* __restrict__ h0out,
                                                    u16* __restrict__ hb0out, int N) {
  __shared__ __align__(16) char smem[40960];
  cell_body<1>(smem, blockIdx.x * 64, threadIdx.x, hb0c, ah0, nullptr, nullptr,
               W, bias, Pt, h0in, h0out, hb0out, nullptr, nullptr, nullptr, N);
}

// merged step: even blocks = cell1(t)+out(t), odd blocks = cell0(t+1)
template <int WITHC0>
__global__ __launch_bounds__(512) void step_kernel(const u16* __restrict__ hb0c,
                                                   const u16* __restrict__ ah0,
                                                   const u16* __restrict__ hb1r,
                                                   const u16* __restrict__ ah1,
                                                   const u16* __restrict__ Wp,
                                                   const float* __restrict__ biasbuf,
                                                   float* __restrict__ Pn,
                                                   const float* __restrict__ h1in,
                                                   float* __restrict__ h1out,
                                                   u16* __restrict__ hb1w,
                                                   const float* __restrict__ h0in,
                                                   float* __restrict__ h0out,
                                                   u16* __restrict__ hb0out,
                                                   const u16* __restrict__ WoT,
                                                   const float* __restrict__ bout,
                                                   float* __restrict__ outp, int N) {
  __shared__ __align__(16) char smem[40960];
  int bx = blockIdx.x;
  int role = WITHC0 ? (bx & 1) : 0;
  int row0 = (WITHC0 ? (bx >> 1) : bx) * 64;
  if (role == 0) {
    cell_body<2>(smem, row0, threadIdx.x, hb0c, ah0, hb1r, ah1,
                 Wp + 131072, biasbuf + 256, nullptr,
                 h1in, h1out, hb1w, WoT, bout, outp, N);
  } else {
    cell_body<1>(smem, row0, threadIdx.x, hb0c, ah0, nullptr, nullptr,
                 Wp + 256, biasbuf, Pn,
                 h0in, h0out, hb0out, nullptr, nullptr, nullptr, N);
  }
}

extern "C" void kernel_launch(void* const* d_in, const int* in_sizes, int n_in,
                              void* d_out, int out_size, void* d_ws, size_t ws_size,
                              hipStream_t stream) {
  const float* x      = (const float*)d_in[0];  // [T,N,D]
  const float* hs     = (const float*)d_in[1];  // [L,N,D]
  const float* Wself  = (const float*)d_in[2];  // [L,6,D,D]
  const float* Wneigh = (const float*)d_in[3];
  const float* b      = (const float*)d_in[4];  // [L,6,D]
  const float* Wout   = (const float*)d_in[5];  // [D,OUT]
  const float* bout   = (const float*)d_in[6];  // [OUT]
  const int*   src    = (const int*)d_in[7];    // [E]
  const int*   dst    = (const int*)d_in[8];    // [E]
  float* out = (float*)d_out;

  const int N = NN, E = EE, D = DD, T = TT;

  char* ws = (char*)d_ws;
  size_t off = 0;
  auto alloc = [&](size_t bytes) -> void* {
    void* p = ws + off;
    off = (off + bytes + 255) & ~(size_t)255;
    return p;
  };
  int*   deg     = (int*)alloc(N * 4);
  int*   offs    = (int*)alloc((N + 1) * 4);
  int*   cursor  = (int*)alloc(N * 4);
  int*   csr     = (int*)alloc(E * 4);
  float* dinv    = (float*)alloc(N * 4);
  u16*   Wp      = (u16*)alloc(2 * 256 * 512 * 2);
  float* biasbuf = (float*)alloc(512 * 4);
  u16*   WoT     = (u16*)alloc(64 * 128 * 2);
  float* h0A     = (float*)alloc((size_t)N * D * 4);
  float* h0B     = (float*)alloc((size_t)N * D * 4);
  float* h1f     = (float*)alloc((size_t)N * D * 4);
  u16*   hb0A    = (u16*)alloc((size_t)N * D * 2);
  u16*   hb0B    = (u16*)alloc((size_t)N * D * 2);
  u16*   hb1     = (u16*)alloc((size_t)N * D * 2);
  u16*   ah0b    = (u16*)alloc((size_t)N * D * 2);
  u16*   ah1b    = (u16*)alloc((size_t)N * D * 2);
  u16*   xb      = (u16*)alloc((size_t)T * N * D * 2);
  u16*   axb     = (u16*)alloc((size_t)T * N * D * 2);
  float* P       = (float*)alloc((size_t)T * N * 256 * 4);

  float* h0f[2] = {h0A, h0B};
  u16*   hb0[2] = {hb0A, hb0B};
  float* hid0 = out + (size_t)T * N * OO;              // final hidden[0]
  float* hid1 = hid0 + (size_t)N * D;                  // final hidden[1]

  hipMemsetAsync(deg, 0, N * 4, stream);
  hipMemsetAsync(cursor, 0, N * 4, stream);
  {
    int nx4 = T * N * D / 4, nh4half = N * D / 4;
    int tot = nx4 + 2 * nh4half + E + (2 * 256 * 512 + 64 * 128 + 512);
    prep_kernel<<<(tot + 255) / 256, 256, 0, stream>>>(
        x, hs, dst, Wself, Wneigh, b, Wout,
        xb, h0A, hb0A, h1f, hb1, deg, Wp, biasbuf, WoT, nx4, nh4half, E);
  }
  scan_kernel<<<1, 1024, 0, stream>>>(deg, offs, dinv, N);
  fill_kernel<<<(E + 255) / 256, 256, 0, stream>>>(src, dst, offs, cursor, csr, E);

  int aggGrid = (N + 3) / 4;   // 2500
  int mmGrid  = (N + 63) / 64; // 157

  // t-sharded agg(x_t) for all t, then batched P[t]
  aggx_kernel<<<30000, 256, 0, stream>>>(offs, csr, dinv, xb, axb, N);
  pre_kernel<<<dim3(mmGrid, T), 512, 0, stream>>>(xb, axb, Wp, P, N);
  // agg(h0_init) for cell0(0)
  aggs_kernel<<<aggGrid, 256, 0, stream>>>(offs, csr, dinv, hb0A, ah0b, N);
  // cell0(0): reads h0A, writes h0B
  cell0_kernel<<<mmGrid, 512, 0, stream>>>(hb0A, ah0b, Wp + 256, biasbuf, P,
                                           h0A, h0B, hb0B, N);

  for (int t = 0; t < T; ++t) {
    u16* cur = hb0[(t + 1) & 1];   // h0'(t) bf16
    // XCD-sharded dual agg: agg(h0'(t)) and agg(h1'(t-1) or h1_init)
    aggdual_kernel<<<2 * aggGrid, 256, 0, stream>>>(offs, csr, dinv, cur, hb1,
                                                    ah0b, ah1b, N);
    if (t < T - 1) {
      // cell1(t) (+out) merged with cell0(t+1) (ping-pong h0).
      // At t==10, cell0(11) produces the FINAL h0 -> write fp32 straight to out.
      float* h0o = (t == T - 2) ? hid0 : h0f[t & 1];
      step_kernel<1><<<2 * mmGrid, 512, 0, stream>>>(
          cur, ah0b, hb1, ah1b, Wp, biasbuf,
          P + (size_t)(t + 1) * N * 256,
          h1f, h1f, hb1,
          h0f[(t + 1) & 1], h0o, hb0[t & 1],
          WoT, bout, out + (size_t)t * N * OO, N);
    } else {
      // t==11: final cell1 -> write final h1 fp32 straight to out
      step_kernel<0><<<mmGrid, 512, 0, stream>>>(
          cur, ah0b, hb1, ah1b, Wp, biasbuf, nullptr,
          h1f, hid1, hb1, nullptr, nullptr, nullptr,
          WoT, bout, out + (size_t)t * N * OO, N);
    }
  }
}

// Round 6
// 637.603 us; speedup vs baseline: 2.7548x; 1.0681x over previous
//
#include <hip/hip_runtime.h>

typedef unsigned short u16;
typedef unsigned int   u32;
typedef __attribute__((ext_vector_type(4))) float f32x4;
typedef __attribute__((ext_vector_type(8))) short s16x8;

#define TT 12
#define NN 10000
#define EE 160000
#define DD 128
#define OO 64

__device__ __forceinline__ u16 f2bf(float f) {
  union { float f; u32 u; } x; x.f = f;
  u32 r = x.u + 0x7FFFu + ((x.u >> 16) & 1u);   // RNE
  return (u16)(r >> 16);
}
__device__ __forceinline__ float bf2f(u16 v) {
  union { u32 u; float f; } x; x.u = (u32)v << 16; return x.f;
}

// ---------------- fused prep: pack(W,b,Wout) FIRST, then cvt(x,hs), then count ----------------
// pack segment leads the grid so its latency-bound strided reads overlap the bulk cvt.
__global__ __launch_bounds__(256) void prep_kernel(
    const float* __restrict__ x, const float* __restrict__ hs,
    const int* __restrict__ dst,
    const float* __restrict__ Wself, const float* __restrict__ Wneigh,
    const float* __restrict__ b, const float* __restrict__ Wout,
    u16* __restrict__ xb, float* __restrict__ h0f, u16* __restrict__ hb0,
    float* __restrict__ h1f, u16* __restrict__ hb1,
    int* __restrict__ deg, u16* __restrict__ Wp,
    float* __restrict__ biasbuf, u16* __restrict__ WoT,
    int nx8, int nh8half, int E) {
  int gid = blockIdx.x * 256 + threadIdx.x;
  const int NWP = 2 * 256 * 512;
  const int NPACK = NWP + 64 * 128 + 512;
  int cvtXEnd = NPACK + nx8;
  int cvtHEnd = cvtXEnd + 2 * nh8half;
  int cntEnd  = cvtHEnd + E;
  if (gid < NPACK) {
    int pg = gid;
    if (pg < NWP) {
      int j = pg >> 17;
      int rem = pg & 131071;
      int c = rem >> 9;
      int k = rem & 511;
      int seg = k >> 7, kd = k & 127;
      int cc = c & 127;
      int gate = (c < 128) ? (seg < 2 ? 2 : 3) : (seg < 2 ? 4 : 5);
      const float* M = (seg & 1) ? Wneigh : Wself;
      float v = M[((j * 6 + gate) * 128 + kd) * 128 + cc];
      Wp[pg] = f2bf(v);
    } else if (pg < NWP + 64 * 128) {
      int i = pg - NWP;
      int c = i >> 7, k = i & 127;               // WoT[c][k] = Wout[k][c]
      WoT[i] = f2bf(Wout[k * OO + c]);
    } else {
      int i = pg - NWP - 64 * 128;
      int j = i >> 8, g = (i >> 7) & 1, d = i & 127;
      int g1 = g ? 4 : 2, g2 = g ? 5 : 3;
      biasbuf[i] = b[(j * 6 + g1) * 128 + d] + b[(j * 6 + g2) * 128 + d];
    }
  } else if (gid < cvtXEnd) {
    int i8 = gid - NPACK;
    float4 va = *(const float4*)(x + (size_t)i8 * 8);
    float4 vb = *(const float4*)(x + (size_t)i8 * 8 + 4);
    uint4 p;
    p.x = (u32)f2bf(va.x) | ((u32)f2bf(va.y) << 16);
    p.y = (u32)f2bf(va.z) | ((u32)f2bf(va.w) << 16);
    p.z = (u32)f2bf(vb.x) | ((u32)f2bf(vb.y) << 16);
    p.w = (u32)f2bf(vb.z) | ((u32)f2bf(vb.w) << 16);
    *(uint4*)(xb + (size_t)i8 * 8) = p;
  } else if (gid < cvtHEnd) {
    int j = gid - cvtXEnd;
    int half = (j >= nh8half);
    int jj = half ? j - nh8half : j;
    float4 va = ((const float4*)hs)[(size_t)j * 2];
    float4 vb = ((const float4*)hs)[(size_t)j * 2 + 1];
    float* fdst = half ? h1f : h0f;
    u16*   bdst = half ? hb1 : hb0;
    ((float4*)fdst)[(size_t)jj * 2]     = va;
    ((float4*)fdst)[(size_t)jj * 2 + 1] = vb;
    uint4 p;
    p.x = (u32)f2bf(va.x) | ((u32)f2bf(va.y) << 16);
    p.y = (u32)f2bf(va.z) | ((u32)f2bf(va.w) << 16);
    p.z = (u32)f2bf(vb.x) | ((u32)f2bf(vb.y) << 16);
    p.w = (u32)f2bf(vb.z) | ((u32)f2bf(vb.w) << 16);
    ((uint4*)bdst)[jj] = p;
  } else if (gid < cntEnd) {
    int e = gid - cvtHEnd;
    atomicAdd(&deg[dst[e]], 1);
  }
}

// ---------------- scan: single block, one barrier phase ----------------
__global__ __launch_bounds__(1024) void scan_kernel(const int* __restrict__ deg,
                                                    int* __restrict__ offs,
                                                    float* __restrict__ dinv, int n) {
  __shared__ int lds_deg[10240];
  __shared__ int wsum[16];
  int tid = threadIdx.x;
  for (int i = tid; i < 10240; i += 1024) lds_deg[i] = (i < n) ? deg[i] : 0;
  __syncthreads();
  int base = tid * 10;
  int loc[10];
  int s = 0;
  #pragma unroll
  for (int k = 0; k < 10; ++k) { loc[k] = s; s += lds_deg[base + k]; }
  int lane = tid & 63;
  int incl = s;
  #pragma unroll
  for (int d = 1; d < 64; d <<= 1) {
    int t2 = __shfl_up(incl, d);
    if (lane >= d) incl += t2;
  }
  int wid = tid >> 6;
  if (lane == 63) wsum[wid] = incl;
  __syncthreads();
  int wpre = 0;
  for (int k = 0; k < wid; ++k) wpre += wsum[k];
  int excl = wpre + incl - s;                      // exclusive prefix of this run
  #pragma unroll
  for (int k = 0; k < 10; ++k) {
    int idx = base + k;
    if (idx < n) {
      int d0 = lds_deg[idx];
      offs[idx] = excl + loc[k];
      dinv[idx] = (d0 > 0) ? 1.0f / (float)d0 : 0.0f;
    }
  }
  if (tid == 1023) offs[n] = excl + s;
}

__global__ __launch_bounds__(256) void fill_kernel(const int* __restrict__ src,
                                                   const int* __restrict__ dst,
                                                   const int* __restrict__ offs,
                                                   int* __restrict__ cursor,
                                                   int* __restrict__ csr, int E) {
  int e = blockIdx.x * 256 + threadIdx.x;
  if (e >= E) return;
  int d = dst[e];
  int pos = atomicAdd(&cursor[d], 1);
  csr[offs[d] + pos] = src[e] * 64;                // pre-scaled (u32 stride per node)
}

// ---------------- gather-mean core: one wave = one node; 8-deep MLP ----------------
__device__ __forceinline__ void agg_one(const int* __restrict__ offs,
                                        const int* __restrict__ csr,
                                        const float* __restrict__ dinv,
                                        const u32* __restrict__ S,
                                        u32* __restrict__ O,
                                        int node, int lane) {
  int nu = __builtin_amdgcn_readfirstlane(node);   // wave-uniform -> scalar loads
  int e0 = offs[nu], e1 = offs[nu + 1];
  float di = dinv[nu];
  float xa = 0.f, ya = 0.f, xb_ = 0.f, yb_ = 0.f;
  float xc = 0.f, yc = 0.f, xd = 0.f, yd = 0.f;
  int e = e0;
  for (; e + 8 <= e1; e += 8) {
    int i0 = csr[e],     i1 = csr[e + 1], i2 = csr[e + 2], i3 = csr[e + 3];
    int i4 = csr[e + 4], i5 = csr[e + 5], i6 = csr[e + 6], i7 = csr[e + 7];
    u32 v0 = S[i0 + lane], v1 = S[i1 + lane], v2 = S[i2 + lane], v3 = S[i3 + lane];
    u32 v4 = S[i4 + lane], v5 = S[i5 + lane], v6 = S[i6 + lane], v7 = S[i7 + lane];
    xa  += bf2f((u16)v0) + bf2f((u16)v1);
    ya  += bf2f((u16)(v0 >> 16)) + bf2f((u16)(v1 >> 16));
    xb_ += bf2f((u16)v2) + bf2f((u16)v3);
    yb_ += bf2f((u16)(v2 >> 16)) + bf2f((u16)(v3 >> 16));
    xc  += bf2f((u16)v4) + bf2f((u16)v5);
    yc  += bf2f((u16)(v4 >> 16)) + bf2f((u16)(v5 >> 16));
    xd  += bf2f((u16)v6) + bf2f((u16)v7);
    yd  += bf2f((u16)(v6 >> 16)) + bf2f((u16)(v7 >> 16));
  }
  for (; e + 4 <= e1; e += 4) {
    int i0 = csr[e], i1 = csr[e + 1], i2 = csr[e + 2], i3 = csr[e + 3];
    u32 v0 = S[i0 + lane], v1 = S[i1 + lane], v2 = S[i2 + lane], v3 = S[i3 + lane];
    xa  += bf2f((u16)v0) + bf2f((u16)v1);
    ya  += bf2f((u16)(v0 >> 16)) + bf2f((u16)(v1 >> 16));
    xb_ += bf2f((u16)v2) + bf2f((u16)v3);
    yb_ += bf2f((u16)(v2 >> 16)) + bf2f((u16)(v3 >> 16));
  }
  for (; e < e1; ++e) {
    u32 v = S[csr[e] + lane];
    xa += bf2f((u16)v); ya += bf2f((u16)(v >> 16));
  }
  float sx = ((xa + xb_) + (xc + xd)) * di;
  float sy = ((ya + yb_) + (yc + yd)) * di;
  O[nu * 64 + lane] = (u32)f2bf(sx) | ((u32)f2bf(sy) << 16);
}

// single-source agg (initial h0 agg)
__global__ __launch_bounds__(256) void aggs_kernel(const int* __restrict__ offs,
                                                   const int* __restrict__ csr,
                                                   const float* __restrict__ dinv,
                                                   const u16* __restrict__ s,
                                                   u16* __restrict__ o, int N) {
  int node = blockIdx.x * 4 + (threadIdx.x >> 6);
  if (node >= N) return;
  agg_one(offs, csr, dinv, (const u32*)s, (u32*)o, node, threadIdx.x & 63);
}

// x-agg, t-sharded by XCD slot: each XCD's gather source is ONE 2.56MB t-slice.
__global__ __launch_bounds__(256) void aggx_kernel(const int* __restrict__ offs,
                                                   const int* __restrict__ csr,
                                                   const float* __restrict__ dinv,
                                                   const u16* __restrict__ xb,
                                                   u16* __restrict__ axb, int N) {
  int id = blockIdx.x;
  int t, grp;
  if (id < 20000) {
    t = id & 7;
    grp = id >> 3;                               // [0,2500)
  } else {
    int j = id - 20000;                          // [0,10000)
    int slot = j & 7;
    t = 8 + (slot & 3);
    grp = (slot >> 2) * 1250 + (j >> 3);         // [0,2500)
  }
  int node = grp * 4 + (threadIdx.x >> 6);
  if (node >= N) return;
  size_t yo = (size_t)t * N * 64;
  agg_one(offs, csr, dinv, (const u32*)xb + yo, (u32*)axb + yo, node, threadIdx.x & 63);
}

// dual agg, XCD-sharded: XCD slots 0-3 -> source0, 4-7 -> source1.
__global__ __launch_bounds__(256) void aggdual_kernel(const int* __restrict__ offs,
                                                      const int* __restrict__ csr,
                                                      const float* __restrict__ dinv,
                                                      const u16* __restrict__ s0,
                                                      const u16* __restrict__ s1,
                                                      u16* __restrict__ o0,
                                                      u16* __restrict__ o1, int N) {
  int b = blockIdx.x;
  int srcsel = (b >> 2) & 1;
  int idx = (b >> 3) * 4 + (b & 3);
  int node = idx * 4 + (threadIdx.x >> 6);
  if (node >= N) return;
  const u32* S = (const u32*)(srcsel ? s1 : s0);
  u32* O = (u32*)(srcsel ? o1 : o0);
  agg_one(offs, csr, dinv, S, O, node, threadIdx.x & 63);
}

// ---------------- cell/GEMM body ----------------
// tile 64 rows x 256 cols, 512 threads (8 waves), K=512: A=[s0|s1|s2|s3]
// MODE 2: cell + h-update + fused out GEMM; MODE 3: cell + h-update only
template <int MODE>
__device__ __forceinline__ void cell_body(char* __restrict__ smem, int row0, int tid,
    const u16* __restrict__ s0, const u16* __restrict__ s1,
    const u16* __restrict__ s2, const u16* __restrict__ s3,
    const u16* __restrict__ W, const float* __restrict__ bias,
    const float* __restrict__ hin, float* __restrict__ hout, u16* __restrict__ hbout,
    const u16* __restrict__ WoT, const float* __restrict__ bout,
    float* __restrict__ outp, int N) {
  u16* As = (u16*)smem;              // 64x64 bf16 swizzled (8KB)
  u16* Bs = (u16*)(smem + 8192);     // 256x64 bf16 swizzled (32KB)
  const u16* srcs[4] = {s0, s1, s2, s3};
  int lane = tid & 63, w = tid >> 6;
  int wr = w & 3, wc = w >> 2;

  f32x4 accU[4], accC[4];
  #pragma unroll
  for (int n = 0; n < 4; ++n) { accU[n] = (f32x4){0,0,0,0}; accC[n] = (f32x4){0,0,0,0}; }

  #pragma unroll
  for (int kc = 0; kc < 8; ++kc) {
    {
      int r = tid >> 3, k8 = (tid & 7) * 8;
      const u16* sp = srcs[kc >> 1];
      int grow = row0 + r;
      uint4 v = make_uint4(0, 0, 0, 0);
      if (grow < N) v = *(const uint4*)(sp + (size_t)grow * DD + (kc & 1) * 64 + k8);
      int byte = (r * 128 + (tid & 7) * 16) ^ ((r & 7) << 4);
      *(uint4*)((char*)As + byte) = v;
    }
    #pragma unroll
    for (int it = 0; it < 4; ++it) {
      int id = it * 512 + tid;
      int c = id >> 3, k8 = (id & 7) * 8;
      uint4 v = *(const uint4*)(W + c * 512 + kc * 64 + k8);
      int byte = (c * 128 + (id & 7) * 16) ^ ((c & 7) << 4);
      *(uint4*)((char*)Bs + byte) = v;
    }
    __syncthreads();
    #pragma unroll
    for (int ks = 0; ks < 2; ++ks) {
      int arow = wr * 16 + (lane & 15);
      int abyte = (arow * 128 + ks * 64 + (lane >> 4) * 16) ^ ((arow & 7) << 4);
      s16x8 af = *(const s16x8*)((char*)As + abyte);
      #pragma unroll
      for (int n = 0; n < 4; ++n) {
        int cu = wc * 64 + n * 16 + (lane & 15);
        int bub = (cu * 128 + ks * 64 + (lane >> 4) * 16) ^ ((cu & 7) << 4);
        s16x8 bu = *(const s16x8*)((char*)Bs + bub);
        accU[n] = __builtin_amdgcn_mfma_f32_16x16x32_bf16(af, bu, accU[n], 0, 0, 0);
        int cc = cu + 128;
        int bcb = (cc * 128 + ks * 64 + (lane >> 4) * 16) ^ ((cc & 7) << 4);
        s16x8 bc = *(const s16x8*)((char*)Bs + bcb);
        accC[n] = __builtin_amdgcn_mfma_f32_16x16x32_bf16(af, bc, accC[n], 0, 0, 0);
      }
    }
    __syncthreads();
  }

  // ---- epilogue: u=sigmoid, c=tanh, h' = u*h + (1-u)*c ----
  #pragma unroll
  for (int n = 0; n < 4; ++n) {
    int col = wc * 64 + n * 16 + (lane & 15);
    float bu = bias[col], bc = bias[128 + col];
    #pragma unroll
    for (int r = 0; r < 4; ++r) {
      int row = row0 + wr * 16 + (lane >> 4) * 4 + r;
      if (row < N) {
        float u = 1.0f / (1.0f + __expf(-(accU[n][r] + bu)));
        float cg = tanhf(accC[n][r] + bc);
        size_t idx = (size_t)row * DD + col;
        float hn = u * hin[idx] + (1.0f - u) * cg;
        hout[idx] = hn;
        u16 hnb = f2bf(hn);
        hbout[idx] = hnb;
        if constexpr (MODE == 2) {
          int rl = row - row0;
          int hbyte = (rl * 256 + col * 2) ^ ((rl & 7) << 4);
          *(u16*)(smem + hbyte) = hnb;       // h1' tile overlays As/Bs (dead now)
        }
      }
    }
  }
  if constexpr (MODE == 2) {
    #pragma unroll
    for (int it = 0; it < 2; ++it) {
      int id = it * 512 + tid;
      int c = id >> 4, kc8 = (id & 15) * 8;
      uint4 v = *(const uint4*)(WoT + c * 128 + kc8);
      int byte = (c * 256 + kc8 * 2) ^ ((c & 7) << 4);
      *(uint4*)(smem + 16384 + byte) = v;
    }
    __syncthreads();
    f32x4 ao[2] = {};
    #pragma unroll
    for (int ks = 0; ks < 4; ++ks) {
      int arow = wr * 16 + (lane & 15);
      int abyte = (arow * 256 + ks * 64 + (lane >> 4) * 16) ^ ((arow & 7) << 4);
      s16x8 af = *(const s16x8*)(smem + abyte);
      #pragma unroll
      for (int n = 0; n < 2; ++n) {
        int co = wc * 32 + n * 16 + (lane & 15);
        int bbyte = (co * 256 + ks * 64 + (lane >> 4) * 16) ^ ((co & 7) << 4);
        s16x8 bf = *(const s16x8*)(smem + 16384 + bbyte);
        ao[n] = __builtin_amdgcn_mfma_f32_16x16x32_bf16(af, bf, ao[n], 0, 0, 0);
      }
    }
    #pragma unroll
    for (int n = 0; n < 2; ++n) {
      int co = wc * 32 + n * 16 + (lane & 15);
      float bb = bout[co];
      #pragma unroll
      for (int r = 0; r < 4; ++r) {
        int row = row0 + wr * 16 + (lane >> 4) * 4 + r;
        if (row < N) outp[(size_t)row * OO + co] = ao[n][r] + bb;
      }
    }
  }
}

// standalone cell0: h0' = cell(x_t, ax_t, h0, ah0), K=512
__global__ __launch_bounds__(512) void cell0_kernel(const u16* __restrict__ xbt,
                                                    const u16* __restrict__ axbt,
                                                    const u16* __restrict__ hb0c,
                                                    const u16* __restrict__ ah0,
                                                    const u16* __restrict__ W,
                                                    const float* __restrict__ bias,
                                                    const float* __restrict__ h0in,
                                                    float* __restrict__ h0out,
                                                    u16* __restrict__ hb0out, int N) {
  __shared__ __align__(16) char smem[40960];
  cell_body<3>(smem, blockIdx.x * 64, threadIdx.x, xbt, axbt, hb0c, ah0,
               W, bias, h0in, h0out, hb0out, nullptr, nullptr, nullptr, N);
}

// merged step: even blocks = cell1(t)+out(t), odd blocks = cell0(t+1)
template <int WITHC0>
__global__ __launch_bounds__(512) void step_kernel(const u16* __restrict__ xbn,
                                                   const u16* __restrict__ axbn,
                                                   const u16* __restrict__ hb0c,
                                                   const u16* __restrict__ ah0,
                                                   const u16* __restrict__ hb1r,
                                                   const u16* __restrict__ ah1,
                                                   const u16* __restrict__ Wp,
                                                   const float* __restrict__ biasbuf,
                                                   const float* __restrict__ h1in,
                                                   float* __restrict__ h1out,
                                                   u16* __restrict__ hb1w,
                                                   const float* __restrict__ h0in,
                                                   float* __restrict__ h0out,
                                                   u16* __restrict__ hb0out,
                                                   const u16* __restrict__ WoT,
                                                   const float* __restrict__ bout,
                                                   float* __restrict__ outp, int N) {
  __shared__ __align__(16) char smem[40960];
  int bx = blockIdx.x;
  int role = WITHC0 ? (bx & 1) : 0;
  int row0 = (WITHC0 ? (bx >> 1) : bx) * 64;
  if (role == 0) {
    cell_body<2>(smem, row0, threadIdx.x, hb0c, ah0, hb1r, ah1,
                 Wp + 131072, biasbuf + 256,
                 h1in, h1out, hb1w, WoT, bout, outp, N);
  } else {
    cell_body<3>(smem, row0, threadIdx.x, xbn, axbn, hb0c, ah0,
                 Wp, biasbuf,
                 h0in, h0out, hb0out, nullptr, nullptr, nullptr, N);
  }
}

extern "C" void kernel_launch(void* const* d_in, const int* in_sizes, int n_in,
                              void* d_out, int out_size, void* d_ws, size_t ws_size,
                              hipStream_t stream) {
  const float* x      = (const float*)d_in[0];  // [T,N,D]
  const float* hs     = (const float*)d_in[1];  // [L,N,D]
  const float* Wself  = (const float*)d_in[2];  // [L,6,D,D]
  const float* Wneigh = (const float*)d_in[3];
  const float* b      = (const float*)d_in[4];  // [L,6,D]
  const float* Wout   = (const float*)d_in[5];  // [D,OUT]
  const float* bout   = (const float*)d_in[6];  // [OUT]
  const int*   src    = (const int*)d_in[7];    // [E]
  const int*   dst    = (const int*)d_in[8];    // [E]
  float* out = (float*)d_out;

  const int N = NN, E = EE, D = DD, T = TT;

  char* ws = (char*)d_ws;
  size_t off = 0;
  auto alloc = [&](size_t bytes) -> void* {
    void* p = ws + off;
    off = (off + bytes + 255) & ~(size_t)255;
    return p;
  };
  int*   deg     = (int*)alloc(N * 4);
  int*   offs    = (int*)alloc((N + 1) * 4);
  int*   cursor  = (int*)alloc(N * 4);
  int*   csr     = (int*)alloc(E * 4);
  float* dinv    = (float*)alloc(N * 4);
  u16*   Wp      = (u16*)alloc(2 * 256 * 512 * 2);
  float* biasbuf = (float*)alloc(512 * 4);
  u16*   WoT     = (u16*)alloc(64 * 128 * 2);
  float* h0A     = (float*)alloc((size_t)N * D * 4);
  float* h0B     = (float*)alloc((size_t)N * D * 4);
  float* h1f     = (float*)alloc((size_t)N * D * 4);
  u16*   hb0A    = (u16*)alloc((size_t)N * D * 2);
  u16*   hb0B    = (u16*)alloc((size_t)N * D * 2);
  u16*   hb1     = (u16*)alloc((size_t)N * D * 2);
  u16*   ah0b    = (u16*)alloc((size_t)N * D * 2);
  u16*   ah1b    = (u16*)alloc((size_t)N * D * 2);
  u16*   xb      = (u16*)alloc((size_t)T * N * D * 2);
  u16*   axb     = (u16*)alloc((size_t)T * N * D * 2);

  float* h0f[2] = {h0A, h0B};
  u16*   hb0[2] = {hb0A, hb0B};
  float* hid0 = out + (size_t)T * N * OO;              // final hidden[0]
  float* hid1 = hid0 + (size_t)N * D;                  // final hidden[1]

  hipMemsetAsync(deg, 0, N * 4, stream);
  hipMemsetAsync(cursor, 0, N * 4, stream);
  {
    int nx8 = T * N * D / 8, nh8half = N * D / 8;
    int NPACK = 2 * 256 * 512 + 64 * 128 + 512;
    int tot = NPACK + nx8 + 2 * nh8half + E;
    prep_kernel<<<(tot + 255) / 256, 256, 0, stream>>>(
        x, hs, dst, Wself, Wneigh, b, Wout,
        xb, h0A, hb0A, h1f, hb1, deg, Wp, biasbuf, WoT, nx8, nh8half, E);
  }
  scan_kernel<<<1, 1024, 0, stream>>>(deg, offs, dinv, N);
  fill_kernel<<<(E + 255) / 256, 256, 0, stream>>>(src, dst, offs, cursor, csr, E);

  int aggGrid = (N + 3) / 4;   // 2500
  int mmGrid  = (N + 63) / 64; // 157

  // t-sharded agg(x_t) for all t
  aggx_kernel<<<30000, 256, 0, stream>>>(offs, csr, dinv, xb, axb, N);
  // agg(h0_init) for cell0(0)
  aggs_kernel<<<aggGrid, 256, 0, stream>>>(offs, csr, dinv, hb0A, ah0b, N);
  // cell0(0): K=512 [x_0 | ax_0 | h0 | ah0]; reads h0A, writes h0B
  cell0_kernel<<<mmGrid, 512, 0, stream>>>(xb, axb, hb0A, ah0b, Wp, biasbuf,
                                           h0A, h0B, hb0B, N);

  for (int t = 0; t < T; ++t) {
    u16* cur = hb0[(t + 1) & 1];   // h0'(t) bf16
    // XCD-sharded dual agg: agg(h0'(t)) and agg(h1'(t-1) or h1_init)
    aggdual_kernel<<<2 * aggGrid, 256, 0, stream>>>(offs, csr, dinv, cur, hb1,
                                                    ah0b, ah1b, N);
    if (t < T - 1) {
      // cell1(t)+out merged with cell0(t+1) (K=512, ping-pong h0).
      // At t==10, cell0(11) produces the FINAL h0 -> write fp32 straight to out.
      float* h0o = (t == T - 2) ? hid0 : h0f[t & 1];
      step_kernel<1><<<2 * mmGrid, 512, 0, stream>>>(
          xb + (size_t)(t + 1) * N * D, axb + (size_t)(t + 1) * N * D,
          cur, ah0b, hb1, ah1b, Wp, biasbuf,
          h1f, h1f, hb1,
          h0f[(t + 1) & 1], h0o, hb0[t & 1],
          WoT, bout, out + (size_t)t * N * OO, N);
    } else {
      // t==11: final cell1 -> write final h1 fp32 straight to out
      step_kernel<0><<<mmGrid, 512, 0, stream>>>(
          nullptr, nullptr,
          cur, ah0b, hb1, ah1b, Wp, biasbuf,
          h1f, hid1, hb1, nullptr, nullptr, nullptr,
          WoT, bout, out + (size_t)t * N * OO, N);
    }
  }
}

// Round 7
// 620.632 us; speedup vs baseline: 2.8301x; 1.0273x over previous
//
#include <hip/hip_runtime.h>

typedef unsigned short u16;
typedef unsigned int   u32;
typedef __attribute__((ext_vector_type(4))) float f32x4;
typedef __attribute__((ext_vector_type(8))) short s16x8;

#define TT 12
#define NN 10000
#define EE 160000
#define DD 128
#define OO 64

__device__ __forceinline__ u16 f2bf(float f) {
  union { float f; u32 u; } x; x.f = f;
  u32 r = x.u + 0x7FFFu + ((x.u >> 16) & 1u);   // RNE
  return (u16)(r >> 16);
}
__device__ __forceinline__ float bf2f(u16 v) {
  union { u32 u; float f; } x; x.u = (u32)v << 16; return x.f;
}

// async global->LDS, 16B per lane; LDS dest = wave-uniform base + lane*16
__device__ __forceinline__ void gload_lds16(const u16* g, u16* l) {
  __builtin_amdgcn_global_load_lds(
      (const __attribute__((address_space(1))) u32*)(const void*)g,
      (__attribute__((address_space(3))) u32*)(void*)l, 16, 0, 0);
}

// ---------------- fused prep: pack (coalesced reads, pre-swizzled Wp) + cvt + count ----------------
__global__ __launch_bounds__(256) void prep_kernel(
    const float* __restrict__ x, const float* __restrict__ hs,
    const int* __restrict__ dst,
    const float* __restrict__ Wself, const float* __restrict__ Wneigh,
    const float* __restrict__ b, const float* __restrict__ Wout,
    u16* __restrict__ xb, float* __restrict__ h0f, u16* __restrict__ hb0,
    float* __restrict__ h1f, u16* __restrict__ hb1,
    int* __restrict__ deg, u16* __restrict__ Wp,
    float* __restrict__ biasbuf, u16* __restrict__ WoT,
    int nx8, int nh8half, int E) {
  int gid = blockIdx.x * 256 + threadIdx.x;
  const int NWP = 2 * 256 * 512;
  const int NPACK = NWP + 64 * 128 + 512;
  int cvtXEnd = NPACK + nx8;
  int cvtHEnd = cvtXEnd + 2 * nh8half;
  int cntEnd  = cvtHEnd + E;
  if (gid < NPACK) {
    int pg = gid;
    if (pg < NWP) {
      // source-linear walk: s = ((j*8+gm)*128 + kd)*128 + cc  -> coalesced reads
      int cc = pg & 127;
      int kd = (pg >> 7) & 127;
      int gm = (pg >> 14) & 7;          // 0-3: Wself g2..5, 4-7: Wneigh g2..5
      int j  = pg >> 17;
      int gate = 2 + (gm & 3);
      int neigh = gm >> 2;
      const float* M = neigh ? Wneigh : Wself;
      float v = M[(((j * 6) + gate) * 128 + kd) * 128 + cc];
      int c = cc + ((gate >= 4) ? 128 : 0);
      int seg = (gate & 1) * 2 + neigh;
      int k = seg * 128 + kd;
      int kc = k >> 6, k6 = k & 63;
      int ksw = ((k6 & ~7) ^ ((c & 7) << 3)) | (k6 & 7);   // pre-swizzle for linear LDS stage
      Wp[(size_t)j * 131072 + c * 512 + kc * 64 + ksw] = f2bf(v);
    } else if (pg < NWP + 64 * 128) {
      int i = pg - NWP;
      int c = i >> 7, k = i & 127;               // WoT[c][k] = Wout[k][c]
      WoT[i] = f2bf(Wout[k * OO + c]);
    } else {
      int i = pg - NWP - 64 * 128;
      int j = i >> 8, g = (i >> 7) & 1, d = i & 127;
      int g1 = g ? 4 : 2, g2 = g ? 5 : 3;
      biasbuf[i] = b[(j * 6 + g1) * 128 + d] + b[(j * 6 + g2) * 128 + d];
    }
  } else if (gid < cvtXEnd) {
    int i8 = gid - NPACK;
    float4 va = *(const float4*)(x + (size_t)i8 * 8);
    float4 vb = *(const float4*)(x + (size_t)i8 * 8 + 4);
    uint4 p;
    p.x = (u32)f2bf(va.x) | ((u32)f2bf(va.y) << 16);
    p.y = (u32)f2bf(va.z) | ((u32)f2bf(va.w) << 16);
    p.z = (u32)f2bf(vb.x) | ((u32)f2bf(vb.y) << 16);
    p.w = (u32)f2bf(vb.z) | ((u32)f2bf(vb.w) << 16);
    *(uint4*)(xb + (size_t)i8 * 8) = p;
  } else if (gid < cvtHEnd) {
    int j = gid - cvtXEnd;
    int half = (j >= nh8half);
    int jj = half ? j - nh8half : j;
    float4 va = ((const float4*)hs)[(size_t)j * 2];
    float4 vb = ((const float4*)hs)[(size_t)j * 2 + 1];
    float* fdst = half ? h1f : h0f;
    u16*   bdst = half ? hb1 : hb0;
    ((float4*)fdst)[(size_t)jj * 2]     = va;
    ((float4*)fdst)[(size_t)jj * 2 + 1] = vb;
    uint4 p;
    p.x = (u32)f2bf(va.x) | ((u32)f2bf(va.y) << 16);
    p.y = (u32)f2bf(va.z) | ((u32)f2bf(va.w) << 16);
    p.z = (u32)f2bf(vb.x) | ((u32)f2bf(vb.y) << 16);
    p.w = (u32)f2bf(vb.z) | ((u32)f2bf(vb.w) << 16);
    ((uint4*)bdst)[jj] = p;
  } else if (gid < cntEnd) {
    int e = gid - cvtHEnd;
    atomicAdd(&deg[dst[e]], 1);
  }
}

// ---------------- scan: single block, one barrier phase ----------------
__global__ __launch_bounds__(1024) void scan_kernel(const int* __restrict__ deg,
                                                    int* __restrict__ offs,
                                                    float* __restrict__ dinv, int n) {
  __shared__ int lds_deg[10240];
  __shared__ int wsum[16];
  int tid = threadIdx.x;
  for (int i = tid; i < 10240; i += 1024) lds_deg[i] = (i < n) ? deg[i] : 0;
  __syncthreads();
  int base = tid * 10;
  int loc[10];
  int s = 0;
  #pragma unroll
  for (int k = 0; k < 10; ++k) { loc[k] = s; s += lds_deg[base + k]; }
  int lane = tid & 63;
  int incl = s;
  #pragma unroll
  for (int d = 1; d < 64; d <<= 1) {
    int t2 = __shfl_up(incl, d);
    if (lane >= d) incl += t2;
  }
  int wid = tid >> 6;
  if (lane == 63) wsum[wid] = incl;
  __syncthreads();
  int wpre = 0;
  for (int k = 0; k < wid; ++k) wpre += wsum[k];
  int excl = wpre + incl - s;
  #pragma unroll
  for (int k = 0; k < 10; ++k) {
    int idx = base + k;
    if (idx < n) {
      int d0 = lds_deg[idx];
      offs[idx] = excl + loc[k];
      dinv[idx] = (d0 > 0) ? 1.0f / (float)d0 : 0.0f;
    }
  }
  if (tid == 1023) offs[n] = excl + s;
}

__global__ __launch_bounds__(256) void fill_kernel(const int* __restrict__ src,
                                                   const int* __restrict__ dst,
                                                   const int* __restrict__ offs,
                                                   int* __restrict__ cursor,
                                                   int* __restrict__ csr, int E) {
  int e = blockIdx.x * 256 + threadIdx.x;
  if (e >= E) return;
  int d = dst[e];
  int pos = atomicAdd(&cursor[d], 1);
  csr[offs[d] + pos] = src[e] * 64;                // pre-scaled (u32 stride per node)
}

// ---------------- gather-mean core: one wave = one node, 2 edges per vector instr ----------------
__device__ __forceinline__ void acc4(u32 vx, u32 vy, float& a, float& b, float& c, float& d) {
  a += bf2f((u16)vx); b += bf2f((u16)(vx >> 16));
  c += bf2f((u16)vy); d += bf2f((u16)(vy >> 16));
}

__device__ __forceinline__ void agg_one2(const int* __restrict__ offs,
                                         const int* __restrict__ csr,
                                         const float* __restrict__ dinv,
                                         const u32* __restrict__ S,
                                         u32* __restrict__ O,
                                         int node, int lane) {
  int nu = __builtin_amdgcn_readfirstlane(node);   // wave-uniform -> scalar loads
  int e0 = offs[nu], e1 = offs[nu + 1];
  float di = dinv[nu];
  int half = lane >> 5;                            // lanes 0-31: even edge, 32-63: odd edge
  int col = (lane & 31) * 2;                       // u32 offset in row (uint2 per lane)
  float a0 = 0, b0 = 0, c0 = 0, d0 = 0, a1 = 0, b1 = 0, c1 = 0, d1 = 0;
  int e = e0;
  for (; e + 8 <= e1; e += 8) {                    // 8 edges / iter, 4 gathers in flight
    int p0 = csr[e],     p1 = csr[e + 1], p2 = csr[e + 2], p3 = csr[e + 3];
    int p4 = csr[e + 4], p5 = csr[e + 5], p6 = csr[e + 6], p7 = csr[e + 7];
    uint2 v0 = *(const uint2*)(S + (half ? p1 : p0) + col);
    uint2 v1 = *(const uint2*)(S + (half ? p3 : p2) + col);
    uint2 v2 = *(const uint2*)(S + (half ? p5 : p4) + col);
    uint2 v3 = *(const uint2*)(S + (half ? p7 : p6) + col);
    acc4(v0.x, v0.y, a0, b0, c0, d0);
    acc4(v1.x, v1.y, a1, b1, c1, d1);
    acc4(v2.x, v2.y, a0, b0, c0, d0);
    acc4(v3.x, v3.y, a1, b1, c1, d1);
  }
  if (e + 4 <= e1) {
    int p0 = csr[e], p1 = csr[e + 1], p2 = csr[e + 2], p3 = csr[e + 3];
    uint2 v0 = *(const uint2*)(S + (half ? p1 : p0) + col);
    uint2 v1 = *(const uint2*)(S + (half ? p3 : p2) + col);
    acc4(v0.x, v0.y, a0, b0, c0, d0);
    acc4(v1.x, v1.y, a1, b1, c1, d1);
    e += 4;
  }
  if (e + 2 <= e1) {
    int p0 = csr[e], p1 = csr[e + 1];
    uint2 v0 = *(const uint2*)(S + (half ? p1 : p0) + col);
    acc4(v0.x, v0.y, a0, b0, c0, d0);
    e += 2;
  }
  if (e < e1) {                                    // odd tail: half 0 only
    uint2 v0 = *(const uint2*)(S + csr[e] + col);
    if (!half) acc4(v0.x, v0.y, a1, b1, c1, d1);
  }
  float sa = a0 + a1, sb = b0 + b1, sc = c0 + c1, sd = d0 + d1;
  sa += __shfl_down(sa, 32);
  sb += __shfl_down(sb, 32);
  sc += __shfl_down(sc, 32);
  sd += __shfl_down(sd, 32);
  if (!half) {
    uint2 o;
    o.x = (u32)f2bf(sa * di) | ((u32)f2bf(sb * di) << 16);
    o.y = (u32)f2bf(sc * di) | ((u32)f2bf(sd * di) << 16);
    *(uint2*)(O + (size_t)nu * 64 + col) = o;
  }
}

// x-agg, t-sharded by XCD slot (one 2.56MB t-slice per XCD) + folded initial h0 agg.
// grid = 32500: [0,20000): t=id&7; [20000,30000): t=8+(slot&3); [30000,32500): h0 init.
__global__ __launch_bounds__(256) void aggx_kernel(const int* __restrict__ offs,
                                                   const int* __restrict__ csr,
                                                   const float* __restrict__ dinv,
                                                   const u16* __restrict__ xb,
                                                   u16* __restrict__ axb,
                                                   const u16* __restrict__ hb0,
                                                   u16* __restrict__ ah0, int N) {
  int id = blockIdx.x;
  const u32* S; u32* O; int grp;
  if (id < 20000) {
    int t = id & 7; grp = id >> 3;
    S = (const u32*)xb + (size_t)t * N * 64; O = (u32*)axb + (size_t)t * N * 64;
  } else if (id < 30000) {
    int j = id - 20000;
    int slot = j & 7;
    int t = 8 + (slot & 3);
    grp = (slot >> 2) * 1250 + (j >> 3);
    S = (const u32*)xb + (size_t)t * N * 64; O = (u32*)axb + (size_t)t * N * 64;
  } else {
    grp = id - 30000;
    S = (const u32*)hb0; O = (u32*)ah0;
  }
  int node = grp * 4 + (threadIdx.x >> 6);
  if (node >= N) return;
  agg_one2(offs, csr, dinv, S, O, node, threadIdx.x & 63);
}

// dual agg, XCD-sharded: XCD slots 0-3 -> source0, 4-7 -> source1.
__global__ __launch_bounds__(256) void aggdual_kernel(const int* __restrict__ offs,
                                                      const int* __restrict__ csr,
                                                      const float* __restrict__ dinv,
                                                      const u16* __restrict__ s0,
                                                      const u16* __restrict__ s1,
                                                      u16* __restrict__ o0,
                                                      u16* __restrict__ o1, int N) {
  int b = blockIdx.x;
  int srcsel = (b >> 2) & 1;
  int idx = (b >> 3) * 4 + (b & 3);
  int node = idx * 4 + (threadIdx.x >> 6);
  if (node >= N) return;
  const u32* S = (const u32*)(srcsel ? s1 : s0);
  u32* O = (u32*)(srcsel ? o1 : o0);
  agg_one2(offs, csr, dinv, S, O, node, threadIdx.x & 63);
}

// ---------------- cell/GEMM body ----------------
// tile 64 rows x 256 cols, 512 threads (8 waves), K=512: A=[s0|s1|s2|s3]
// staging via global_load_lds: LDS dest linear (tid*16B), swizzle baked into SOURCE addr
// MODE 2: cell + h-update + fused out GEMM; MODE 3: cell + h-update only
template <int MODE>
__device__ __forceinline__ void cell_body(char* __restrict__ smem, int row0, int tid,
    const u16* __restrict__ s0, const u16* __restrict__ s1,
    const u16* __restrict__ s2, const u16* __restrict__ s3,
    const u16* __restrict__ W, const float* __restrict__ bias,
    const float* __restrict__ hin, float* __restrict__ hout, u16* __restrict__ hbout,
    const u16* __restrict__ WoT, const float* __restrict__ bout,
    float* __restrict__ outp, int N) {
  u16* As = (u16*)smem;              // 64x64 bf16 swizzled (8KB)
  u16* Bs = (u16*)(smem + 8192);     // 256x64 bf16 swizzled (32KB)
  const u16* srcs[4] = {s0, s1, s2, s3};
  int lane = tid & 63, w = tid >> 6;
  int wr = w & 3, wc = w >> 2;

  f32x4 accU[4], accC[4];
  #pragma unroll
  for (int n = 0; n < 4; ++n) { accU[n] = (f32x4){0,0,0,0}; accC[n] = (f32x4){0,0,0,0}; }

  #pragma unroll
  for (int kc = 0; kc < 8; ++kc) {
    // ---- stage A: 64 rows x 64 k; source addr pre-swizzled, LDS linear ----
    {
      int r = tid >> 3, k8 = (tid & 7) * 8;
      int k8s = k8 ^ ((r & 7) << 3);
      const u16* g = srcs[kc >> 1] + (size_t)(row0 + r) * DD + (kc & 1) * 64 + k8s;
      gload_lds16(g, As + (tid & ~63) * 8);     // rows >= N read in-ws garbage, discarded
    }
    // ---- stage B: 256 cols x 64 k from pre-swizzled Wp, LDS linear ----
    #pragma unroll
    for (int it = 0; it < 4; ++it) {
      int id = it * 512 + tid;
      const u16* g = W + (id >> 3) * 512 + kc * 64 + (id & 7) * 8;
      gload_lds16(g, Bs + (it * 512 + (tid & ~63)) * 8);
    }
    __syncthreads();
    #pragma unroll
    for (int ks = 0; ks < 2; ++ks) {
      int arow = wr * 16 + (lane & 15);
      int abyte = (arow * 128 + ks * 64 + (lane >> 4) * 16) ^ ((arow & 7) << 4);
      s16x8 af = *(const s16x8*)((char*)As + abyte);
      #pragma unroll
      for (int n = 0; n < 4; ++n) {
        int cu = wc * 64 + n * 16 + (lane & 15);
        int bub = (cu * 128 + ks * 64 + (lane >> 4) * 16) ^ ((cu & 7) << 4);
        s16x8 bu = *(const s16x8*)((char*)Bs + bub);
        accU[n] = __builtin_amdgcn_mfma_f32_16x16x32_bf16(af, bu, accU[n], 0, 0, 0);
        int cc = cu + 128;
        int bcb = (cc * 128 + ks * 64 + (lane >> 4) * 16) ^ ((cc & 7) << 4);
        s16x8 bc = *(const s16x8*)((char*)Bs + bcb);
        accC[n] = __builtin_amdgcn_mfma_f32_16x16x32_bf16(af, bc, accC[n], 0, 0, 0);
      }
    }
    __syncthreads();
  }

  // ---- epilogue: u=sigmoid, c=tanh, h' = u*h + (1-u)*c ----
  #pragma unroll
  for (int n = 0; n < 4; ++n) {
    int col = wc * 64 + n * 16 + (lane & 15);
    float bu = bias[col], bc = bias[128 + col];
    #pragma unroll
    for (int r = 0; r < 4; ++r) {
      int row = row0 + wr * 16 + (lane >> 4) * 4 + r;
      if (row < N) {
        float u = 1.0f / (1.0f + __expf(-(accU[n][r] + bu)));
        float cg = tanhf(accC[n][r] + bc);
        size_t idx = (size_t)row * DD + col;
        float hn = u * hin[idx] + (1.0f - u) * cg;
        hout[idx] = hn;
        u16 hnb = f2bf(hn);
        hbout[idx] = hnb;
        if constexpr (MODE == 2) {
          int rl = row - row0;
          int hbyte = (rl * 256 + col * 2) ^ ((rl & 7) << 4);
          *(u16*)(smem + hbyte) = hnb;       // h1' tile overlays As/Bs (dead now)
        }
      }
    }
  }
  if constexpr (MODE == 2) {
    #pragma unroll
    for (int it = 0; it < 2; ++it) {
      int id = it * 512 + tid;
      int c = id >> 4, kc8 = (id & 15) * 8;
      uint4 v = *(const uint4*)(WoT + c * 128 + kc8);
      int byte = (c * 256 + kc8 * 2) ^ ((c & 7) << 4);
      *(uint4*)(smem + 16384 + byte) = v;
    }
    __syncthreads();
    f32x4 ao[2] = {};
    #pragma unroll
    for (int ks = 0; ks < 4; ++ks) {
      int arow = wr * 16 + (lane & 15);
      int abyte = (arow * 256 + ks * 64 + (lane >> 4) * 16) ^ ((arow & 7) << 4);
      s16x8 af = *(const s16x8*)(smem + abyte);
      #pragma unroll
      for (int n = 0; n < 2; ++n) {
        int co = wc * 32 + n * 16 + (lane & 15);
        int bbyte = (co * 256 + ks * 64 + (lane >> 4) * 16) ^ ((co & 7) << 4);
        s16x8 bf = *(const s16x8*)(smem + 16384 + bbyte);
        ao[n] = __builtin_amdgcn_mfma_f32_16x16x32_bf16(af, bf, ao[n], 0, 0, 0);
      }
    }
    #pragma unroll
    for (int n = 0; n < 2; ++n) {
      int co = wc * 32 + n * 16 + (lane & 15);
      float bb = bout[co];
      #pragma unroll
      for (int r = 0; r < 4; ++r) {
        int row = row0 + wr * 16 + (lane >> 4) * 4 + r;
        if (row < N) outp[(size_t)row * OO + co] = ao[n][r] + bb;
      }
    }
  }
}

// standalone cell0: h0' = cell(x_t, ax_t, h0, ah0), K=512
__global__ __launch_bounds__(512) void cell0_kernel(const u16* __restrict__ xbt,
                                                    const u16* __restrict__ axbt,
                                                    const u16* __restrict__ hb0c,
                                                    const u16* __restrict__ ah0,
                                                    const u16* __restrict__ W,
                                                    const float* __restrict__ bias,
                                                    const float* __restrict__ h0in,
                                                    float* __restrict__ h0out,
                                                    u16* __restrict__ hb0out, int N) {
  __shared__ __align__(16) char smem[40960];
  cell_body<3>(smem, blockIdx.x * 64, threadIdx.x, xbt, axbt, hb0c, ah0,
               W, bias, h0in, h0out, hb0out, nullptr, nullptr, nullptr, N);
}

// merged step: even blocks = cell1(t)+out(t), odd blocks = cell0(t+1)
template <int WITHC0>
__global__ __launch_bounds__(512) void step_kernel(const u16* __restrict__ xbn,
                                                   const u16* __restrict__ axbn,
                                                   const u16* __restrict__ hb0c,
                                                   const u16* __restrict__ ah0,
                                                   const u16* __restrict__ hb1r,
                                                   const u16* __restrict__ ah1,
                                                   const u16* __restrict__ Wp,
                                                   const float* __restrict__ biasbuf,
                                                   const float* __restrict__ h1in,
                                                   float* __restrict__ h1out,
                                                   u16* __restrict__ hb1w,
                                                   const float* __restrict__ h0in,
                                                   float* __restrict__ h0out,
                                                   u16* __restrict__ hb0out,
                                                   const u16* __restrict__ WoT,
                                                   const float* __restrict__ bout,
                                                   float* __restrict__ outp, int N) {
  __shared__ __align__(16) char smem[40960];
  int bx = blockIdx.x;
  int role = WITHC0 ? (bx & 1) : 0;
  int row0 = (WITHC0 ? (bx >> 1) : bx) * 64;
  if (role == 0) {
    cell_body<2>(smem, row0, threadIdx.x, hb0c, ah0, hb1r, ah1,
                 Wp + 131072, biasbuf + 256,
                 h1in, h1out, hb1w, WoT, bout, outp, N);
  } else {
    cell_body<3>(smem, row0, threadIdx.x, xbn, axbn, hb0c, ah0,
                 Wp, biasbuf,
                 h0in, h0out, hb0out, nullptr, nullptr, nullptr, N);
  }
}

extern "C" void kernel_launch(void* const* d_in, const int* in_sizes, int n_in,
                              void* d_out, int out_size, void* d_ws, size_t ws_size,
                              hipStream_t stream) {
  const float* x      = (const float*)d_in[0];  // [T,N,D]
  const float* hs     = (const float*)d_in[1];  // [L,N,D]
  const float* Wself  = (const float*)d_in[2];  // [L,6,D,D]
  const float* Wneigh = (const float*)d_in[3];
  const float* b      = (const float*)d_in[4];  // [L,6,D]
  const float* Wout   = (const float*)d_in[5];  // [D,OUT]
  const float* bout   = (const float*)d_in[6];  // [OUT]
  const int*   src    = (const int*)d_in[7];    // [E]
  const int*   dst    = (const int*)d_in[8];    // [E]
  float* out = (float*)d_out;

  const int N = NN, E = EE, D = DD, T = TT;

  char* ws = (char*)d_ws;
  size_t off = 0;
  auto alloc = [&](size_t bytes) -> void* {
    void* p = ws + off;
    off = (off + bytes + 255) & ~(size_t)255;
    return p;
  };
  int*   deg     = (int*)alloc(N * 4);
  int*   offs    = (int*)alloc((N + 1) * 4);
  int*   cursor  = (int*)alloc(N * 4);
  int*   csr     = (int*)alloc(E * 4);
  float* dinv    = (float*)alloc(N * 4);
  u16*   Wp      = (u16*)alloc(2 * 256 * 512 * 2);
  float* biasbuf = (float*)alloc(512 * 4);
  u16*   WoT     = (u16*)alloc(64 * 128 * 2);
  float* h0A     = (float*)alloc((size_t)N * D * 4);
  float* h0B     = (float*)alloc((size_t)N * D * 4);
  float* h1f     = (float*)alloc((size_t)N * D * 4);
  u16*   hb0A    = (u16*)alloc((size_t)N * D * 2);
  u16*   hb0B    = (u16*)alloc((size_t)N * D * 2);
  u16*   hb1     = (u16*)alloc((size_t)N * D * 2);
  u16*   ah0b    = (u16*)alloc((size_t)N * D * 2);
  u16*   ah1b    = (u16*)alloc((size_t)N * D * 2);
  u16*   xb      = (u16*)alloc((size_t)T * N * D * 2);
  u16*   axb     = (u16*)alloc((size_t)T * N * D * 2);
  (void)alloc(65536);   // overrun pad for OOB-row staging reads

  float* h0f[2] = {h0A, h0B};
  u16*   hb0[2] = {hb0A, hb0B};
  float* hid0 = out + (size_t)T * N * OO;              // final hidden[0]
  float* hid1 = hid0 + (size_t)N * D;                  // final hidden[1]

  hipMemsetAsync(deg, 0, N * 4, stream);
  hipMemsetAsync(cursor, 0, N * 4, stream);
  {
    int nx8 = T * N * D / 8, nh8half = N * D / 8;
    int NPACK = 2 * 256 * 512 + 64 * 128 + 512;
    int tot = NPACK + nx8 + 2 * nh8half + E;
    prep_kernel<<<(tot + 255) / 256, 256, 0, stream>>>(
        x, hs, dst, Wself, Wneigh, b, Wout,
        xb, h0A, hb0A, h1f, hb1, deg, Wp, biasbuf, WoT, nx8, nh8half, E);
  }
  scan_kernel<<<1, 1024, 0, stream>>>(deg, offs, dinv, N);
  fill_kernel<<<(E + 255) / 256, 256, 0, stream>>>(src, dst, offs, cursor, csr, E);

  int aggGrid = (N + 3) / 4;   // 2500
  int mmGrid  = (N + 63) / 64; // 157

  // t-sharded agg(x_t) for all t + folded agg(h0_init)
  aggx_kernel<<<32500, 256, 0, stream>>>(offs, csr, dinv, xb, axb, hb0A, ah0b, N);
  // cell0(0): K=512 [x_0 | ax_0 | h0 | ah0]; reads h0A, writes h0B
  cell0_kernel<<<mmGrid, 512, 0, stream>>>(xb, axb, hb0A, ah0b, Wp, biasbuf,
                                           h0A, h0B, hb0B, N);

  for (int t = 0; t < T; ++t) {
    u16* cur = hb0[(t + 1) & 1];   // h0'(t) bf16
    // XCD-sharded dual agg: agg(h0'(t)) and agg(h1'(t-1) or h1_init)
    aggdual_kernel<<<2 * aggGrid, 256, 0, stream>>>(offs, csr, dinv, cur, hb1,
                                                    ah0b, ah1b, N);
    if (t < T - 1) {
      // cell1(t)+out merged with cell0(t+1) (K=512, ping-pong h0).
      float* h0o = (t == T - 2) ? hid0 : h0f[t & 1];
      step_kernel<1><<<2 * mmGrid, 512, 0, stream>>>(
          xb + (size_t)(t + 1) * N * D, axb + (size_t)(t + 1) * N * D,
          cur, ah0b, hb1, ah1b, Wp, biasbuf,
          h1f, h1f, hb1,
          h0f[(t + 1) & 1], h0o, hb0[t & 1],
          WoT, bout, out + (size_t)t * N * OO, N);
    } else {
      // t==11: final cell1 -> write final h1 fp32 straight to out
      step_kernel<0><<<mmGrid, 512, 0, stream>>>(
          nullptr, nullptr,
          cur, ah0b, hb1, ah1b, Wp, biasbuf,
          h1f, hid1, hb1, nullptr, nullptr, nullptr,
          WoT, bout, out + (size_t)t * N * OO, N);
    }
  }
}